// Round 2
// baseline (15657.967 us; speedup 1.0000x reference)
//
#include <hip/hip_runtime.h>
#include <cstdint>
#include <utility>

#define NQ 16
#define NDEPTH 4
#define NBATCH 512

// ---------------------------------------------------------------------------
// Compile-time GF(2) tracking of the CNOT ring.
// Physical index x (16 bits): bit b corresponds to wire (15-b).
// Invariant: logical basis index y = A x (bits). Rotation on logical wire q:
//   pair mask  Delta = A^{-1} e_p   (p = 15-q, physical-bit mask)
//   parity row R     = row_p(A)     (logical bit value = parity(x & R))
// CNOT(c,t): Arow[pt] ^= Arow[pc]; Ainv_col[pc] ^= Ainv_col[pt].
// ---------------------------------------------------------------------------
struct Masks {
  unsigned short delta[NDEPTH][NQ];
  unsigned short rowm[NDEPTH][NQ];
  unsigned short meas[NQ];
};

constexpr Masks make_masks() {
  Masks m = {};
  unsigned short Arow[NQ] = {};
  unsigned short Ainv[NQ] = {};
  for (int p = 0; p < NQ; ++p) {
    Arow[p] = (unsigned short)(1u << p);
    Ainv[p] = (unsigned short)(1u << p);
  }
  for (int d = 0; d < NDEPTH; ++d) {
    for (int q = 0; q < NQ; ++q) {
      m.delta[d][q] = Ainv[15 - q];
      m.rowm[d][q]  = Arow[15 - q];
    }
    for (int q = 0; q < NQ - 1; ++q) {    // CNOT(q, q+1)
      const int pc = 15 - q, pt = 15 - (q + 1);
      Arow[pt] = (unsigned short)(Arow[pt] ^ Arow[pc]);
      Ainv[pc] = (unsigned short)(Ainv[pc] ^ Ainv[pt]);
    }
    {                                      // CNOT(15, 0)
      const int pc = 15 - 15, pt = 15 - 0;
      Arow[pt] = (unsigned short)(Arow[pt] ^ Arow[pc]);
      Ainv[pc] = (unsigned short)(Ainv[pc] ^ Ainv[pt]);
    }
  }
  for (int q = 0; q < NQ; ++q) m.meas[q] = Arow[15 - q];
  return m;
}

constexpr Masks MK = make_masks();

// constexpr parity helper (usable in constexpr context, unlike __popc)
constexpr int cpar(int v) {
  int p = 0;
  for (int i = 0; i < 16; ++i) p ^= (v >> i) & 1;
  return p;
}

__device__ __forceinline__ float2 cmul(float2 a, float2 b) {
  return make_float2(a.x * b.x - a.y * b.y, a.x * b.y + a.y * b.x);
}
// acc + a*b
__device__ __forceinline__ float2 cfma(float2 a, float2 b, float2 acc) {
  return make_float2(fmaf(a.x, b.x, fmaf(-a.y, b.y, acc.x)),
                     fmaf(a.x, b.y, fmaf(a.y, b.x, acc.y)));
}

// ---- guaranteed-static loop: every index is a template parameter ----
template<typename F, int... Is>
__device__ __forceinline__ void sf_impl(F&& f, std::integer_sequence<int, Is...>) {
  (f(std::integral_constant<int, Is>{}), ...);
}
template<int N, typename F>
__device__ __forceinline__ void static_for(F&& f) {
  sf_impl(f, std::make_integer_sequence<int, N>{});
}

// ---------------------------------------------------------------------------
// One rotation gate. All s[] indices are template-constants -> VGPRs.
// Layout: x = (tid << 6) | r ;  tid[5:0]=lane, tid[9:6]=wave, r = register.
// Element update: s[r] <- A(par)·s[r] + B(par)·s[r^Delta],
//   A(0)=pt?U11:U00 etc. — coefficient pairs hoisted per gate, element
//   parity under R is constexpr so the A/B choice is compile-time.
// ---------------------------------------------------------------------------
template<int D, int Q>
__device__ __forceinline__ void apply_gate(float2 (&s)[64], float2* xch,
                                           const float2* utab, int tid) {
  constexpr int DLT  = MK.delta[D][Q];
  constexpr int R    = MK.rowm[D][Q];
  constexpr int dreg = DLT & 63;
  constexpr int dthr = (DLT >> 6) & 1023;

  const int gbase = (D * NQ + Q) * 4;
  const float2 U00 = utab[gbase + 0];
  const float2 U01 = utab[gbase + 1];
  const float2 U10 = utab[gbase + 2];
  const float2 U11 = utab[gbase + 3];
  const int pt = __popc((tid << 6) & R) & 1;   // thread-bit parity (runtime)

  // coefficient pairs: element with total parity 0 uses (cA[0],cB[0]), etc.
  const float2 cA0 = pt ? U11 : U00;
  const float2 cB0 = pt ? U10 : U01;
  const float2 cA1 = pt ? U00 : U11;
  const float2 cB1 = pt ? U01 : U10;

  if constexpr (dthr == 0) {
    // ---- Case A: both pair elements in my own registers ----
    constexpr int LB = dreg & (-dreg);
    static_for<64>([&](auto rc) {
      constexpr int r = decltype(rc)::value;
      if constexpr ((r & LB) == 0) {
        constexpr int r2 = r ^ dreg;
        constexpr int p0 = cpar(r & R);
        constexpr int p1 = cpar(r2 & R);
        const float2 a = s[r], c = s[r2];
        const float2 A0 = p0 ? cA1 : cA0, B0 = p0 ? cB1 : cB0;
        const float2 A1 = p1 ? cA1 : cA0, B1 = p1 ? cB1 : cB0;
        s[r]  = cfma(A0, a, cmul(B0, c));
        s[r2] = cfma(A1, c, cmul(B1, a));
      }
    });
  } else if constexpr ((dthr >> 6) == 0) {
    // ---- Case B: partner in another lane of the same wave (shuffle) ----
    constexpr int dlane = dthr;
    if constexpr (dreg == 0) {
      static_for<64>([&](auto rc) {
        constexpr int r = decltype(rc)::value;
        constexpr int p0 = cpar(r & R);
        const float2 m = s[r];
        float2 p;
        p.x = __shfl_xor(m.x, dlane);
        p.y = __shfl_xor(m.y, dlane);
        const float2 A0 = p0 ? cA1 : cA0, B0 = p0 ? cB1 : cB0;
        s[r] = cfma(A0, m, cmul(B0, p));
      });
    } else {
      constexpr int LB = dreg & (-dreg);
      static_for<64>([&](auto rc) {
        constexpr int r = decltype(rc)::value;
        if constexpr ((r & LB) == 0) {
          constexpr int r2 = r ^ dreg;
          constexpr int p0 = cpar(r & R);
          constexpr int p1 = cpar(r2 & R);
          const float2 m0 = s[r], m1 = s[r2];
          float2 p0v, p1v;
          p0v.x = __shfl_xor(m1.x, dlane);   // partner lane's old s[r^dreg]
          p0v.y = __shfl_xor(m1.y, dlane);
          p1v.x = __shfl_xor(m0.x, dlane);   // partner lane's old s[r]
          p1v.y = __shfl_xor(m0.y, dlane);
          const float2 A0 = p0 ? cA1 : cA0, B0 = p0 ? cB1 : cB0;
          const float2 A1 = p1 ? cA1 : cA0, B1 = p1 ? cB1 : cB0;
          s[r]  = cfma(A0, m0, cmul(B0, p0v));
          s[r2] = cfma(A1, m1, cmul(B1, p1v));
        }
      });
    }
  } else {
    // ---- Case C: partner in another thread (possibly other wave) via LDS ----
    const int pthr = tid ^ dthr;
    if constexpr ((dreg >> 3) == 0) {
      // partner reg lives in the same 8-register chunk
      static_for<8>([&](auto kc) {
        constexpr int k = decltype(kc)::value;
        static_for<8>([&](auto jc) {
          constexpr int j = decltype(jc)::value;
          xch[j * 1024 + tid] = s[k * 8 + j];
        });
        __syncthreads();
        static_for<8>([&](auto jc) {
          constexpr int j = decltype(jc)::value;
          constexpr int r = k * 8 + j;
          constexpr int p0 = cpar(r & R);
          const float2 m = s[r];
          const float2 p = xch[(j ^ dreg) * 1024 + pthr];
          const float2 A0 = p0 ? cA1 : cA0, B0 = p0 ? cB1 : cB0;
          s[r] = cfma(A0, m, cmul(B0, p));
        });
        __syncthreads();
      });
    } else {
      // partner reg in a different 4-register chunk: chunk pairs
      constexpr int kx = dreg >> 2;       // >= 2 here
      static_for<16>([&](auto cc) {
        constexpr int c = decltype(cc)::value;
        if constexpr (c < (c ^ kx)) {
          constexpr int c2 = c ^ kx;
          static_for<4>([&](auto jc) {
            constexpr int j = decltype(jc)::value;
            xch[j * 1024 + tid]       = s[c * 4 + j];
            xch[(4 + j) * 1024 + tid] = s[c2 * 4 + j];
          });
          __syncthreads();
          static_for<4>([&](auto jc) {
            constexpr int j = decltype(jc)::value;
            {
              constexpr int r = c * 4 + j;      // partner in chunk c2 -> slots 4..7
              constexpr int p0 = cpar(r & R);
              const float2 m = s[r];
              const float2 p = xch[(4 + ((r ^ dreg) & 3)) * 1024 + pthr];
              const float2 A0 = p0 ? cA1 : cA0, B0 = p0 ? cB1 : cB0;
              s[r] = cfma(A0, m, cmul(B0, p));
            }
            {
              constexpr int r = c2 * 4 + j;     // partner in chunk c -> slots 0..3
              constexpr int p0 = cpar(r & R);
              const float2 m = s[r];
              const float2 p = xch[((r ^ dreg) & 3) * 1024 + pthr];
              const float2 A0 = p0 ? cA1 : cA0, B0 = p0 ? cB1 : cB0;
              s[r] = cfma(A0, m, cmul(B0, p));
            }
          });
          __syncthreads();
        }
      });
    }
  }
}

template<int D, int Q>
__device__ __forceinline__ void apply_all(float2 (&s)[64], float2* xch,
                                          const float2* utab, int tid) {
  apply_gate<D, Q>(s, xch, utab, tid);
  if constexpr (Q < NQ - 1) {
    apply_all<D, Q + 1>(s, xch, utab, tid);
  } else if constexpr (D < NDEPTH - 1) {
    apply_all<D + 1, 0>(s, xch, utab, tid);
  }
}

__global__ __launch_bounds__(1024, 8) void qsim_kernel(const float* __restrict__ x,
                                                       const float* __restrict__ params,
                                                       float* __restrict__ out) {
  __shared__ float2 xch[8192];                 // 64 KB exchange buffer
  __shared__ float2 utab[NDEPTH * NQ * 4];     // 2 KB gate matrices

  const int tid = threadIdx.x;
  const int b = blockIdx.x;

  // ---- per-block gate table: U = RZ(tz) RY(ty) RX(tx) ----
  if (tid < NDEPTH * NQ) {
    const int d = tid / NQ, q = tid % NQ;
    const float a = tanhf(x[b * NQ + q]);
    const float tx = a + params[(d * NQ + q) * 3 + 0];
    const float ty = a + params[(d * NQ + q) * 3 + 1];
    const float tz = a + params[(d * NQ + q) * 3 + 2];
    const float cx = cosf(0.5f * tx), sx = sinf(0.5f * tx);
    const float cy = cosf(0.5f * ty), sy = sinf(0.5f * ty);
    const float cz = cosf(0.5f * tz), sz = sinf(0.5f * tz);
    // RY*RX entries
    const float2 m00 = make_float2(cy * cx,  sy * sx);
    const float2 m01 = make_float2(-sy * cx, -cy * sx);
    const float2 m10 = make_float2(sy * cx,  -cy * sx);
    const float2 m11 = make_float2(cy * cx,  -sy * sx);
    const float2 ez  = make_float2(cz, -sz);   // e^{-i tz/2}
    const float2 ezc = make_float2(cz,  sz);
    utab[tid * 4 + 0] = cmul(ez,  m00);
    utab[tid * 4 + 1] = cmul(ez,  m01);
    utab[tid * 4 + 2] = cmul(ezc, m10);
    utab[tid * 4 + 3] = cmul(ezc, m11);
  }

  // ---- state init: |0..0> ----
  float2 s[64];
  static_for<64>([&](auto rc) {
    constexpr int r = decltype(rc)::value;
    s[r] = make_float2(0.f, 0.f);
  });
  if (tid == 0) s[0].x = 1.0f;
  __syncthreads();

  // ---- all 64 rotation gates (CNOTs folded into the constexpr masks) ----
  apply_all<0, 0>(s, xch, utab, tid);

  // ---- Z expectations: z_q = sum_x (-1)^{parity(x & meas_q)} |s[x]|^2 ----
  float z[NQ];
  static_for<NQ>([&](auto qc) { z[decltype(qc)::value] = 0.f; });
  float sgn[NQ];
  static_for<NQ>([&](auto qc) {
    constexpr int q = decltype(qc)::value;
    sgn[q] = (__popc((tid << 6) & MK.meas[q]) & 1) ? -1.f : 1.f;
  });
  static_for<64>([&](auto rc) {
    constexpr int r = decltype(rc)::value;
    const float pr = s[r].x * s[r].x + s[r].y * s[r].y;
    static_for<NQ>([&](auto qc) {
      constexpr int q = decltype(qc)::value;
      constexpr bool neg = cpar(r & MK.meas[q]) != 0;
      z[q] = fmaf(neg ? -sgn[q] : sgn[q], pr, z[q]);
    });
  });
  // wave-level butterfly reduce
  static_for<NQ>([&](auto qc) {
    constexpr int q = decltype(qc)::value;
    float v = z[q];
    static_for<6>([&](auto ic) {
      constexpr int sh = 32 >> decltype(ic)::value;
      v += __shfl_xor(v, sh);
    });
    z[q] = v;
  });
  __syncthreads();                 // xch free for reuse
  float* red = (float*)xch;
  if ((tid & 63) == 0) {
    const int w = tid >> 6;
    static_for<NQ>([&](auto qc) {
      constexpr int q = decltype(qc)::value;
      red[w * NQ + q] = z[q];
    });
  }
  __syncthreads();
  if (tid < NQ) {
    float acc = 0.f;
#pragma unroll
    for (int w = 0; w < 16; ++w) acc += red[w * NQ + tid];
    out[b * NQ + tid] = acc;
  }
}

extern "C" void kernel_launch(void* const* d_in, const int* in_sizes, int n_in,
                              void* d_out, int out_size, void* d_ws, size_t ws_size,
                              hipStream_t stream) {
  const float* x      = (const float*)d_in[0];
  const float* params = (const float*)d_in[1];
  float* out          = (float*)d_out;
  qsim_kernel<<<dim3(NBATCH), dim3(1024), 0, stream>>>(x, params, out);
}

// Round 4
// 1400.109 us; speedup vs baseline: 11.1834x; 11.1834x over previous
//
#include <hip/hip_runtime.h>
#include <cstdint>
#include <utility>

#define NQ 16
#define NDEPTH 4
#define NBATCH 512
#define NTHR 512      // threads per block (8 waves)
#define NREG 112      // amps resident in registers per thread
#define NAMP 128      // amps per thread
#define NLDS (NAMP - NREG)

// ---------------------------------------------------------------------------
// Compile-time GF(2) tracking of the CNOT ring (mask algebra verified in r1/r2).
// Physical index x (16 bits): bit b corresponds to wire (15-b).
// Rotation on logical wire q at layer d:
//   pair mask  Delta = A^{-1} e_p, parity row R = row_p(A), p = 15-q.
// ---------------------------------------------------------------------------
struct Masks {
  unsigned short delta[NDEPTH][NQ];
  unsigned short rowm[NDEPTH][NQ];
  unsigned short meas[NQ];
};

constexpr Masks make_masks() {
  Masks m = {};
  unsigned short Arow[NQ] = {};
  unsigned short Ainv[NQ] = {};
  for (int p = 0; p < NQ; ++p) {
    Arow[p] = (unsigned short)(1u << p);
    Ainv[p] = (unsigned short)(1u << p);
  }
  for (int d = 0; d < NDEPTH; ++d) {
    for (int q = 0; q < NQ; ++q) {
      m.delta[d][q] = Ainv[15 - q];
      m.rowm[d][q]  = Arow[15 - q];
    }
    for (int q = 0; q < NQ - 1; ++q) {    // CNOT(q, q+1)
      const int pc = 15 - q, pt = 15 - (q + 1);
      Arow[pt] = (unsigned short)(Arow[pt] ^ Arow[pc]);
      Ainv[pc] = (unsigned short)(Ainv[pc] ^ Ainv[pt]);
    }
    {                                      // CNOT(15, 0)
      const int pc = 0, pt = 15;
      Arow[pt] = (unsigned short)(Arow[pt] ^ Arow[pc]);
      Ainv[pc] = (unsigned short)(Ainv[pc] ^ Ainv[pt]);
    }
  }
  for (int q = 0; q < NQ; ++q) m.meas[q] = Arow[15 - q];
  return m;
}

constexpr Masks MK = make_masks();

constexpr int cpar(int v) {
  int p = 0;
  for (int i = 0; i < 16; ++i) p ^= (v >> i) & 1;
  return p;
}

__device__ __forceinline__ float2 cmul(float2 a, float2 b) {
  return make_float2(a.x * b.x - a.y * b.y, a.x * b.y + a.y * b.x);
}
__device__ __forceinline__ float2 cfma(float2 a, float2 b, float2 acc) {
  return make_float2(fmaf(a.x, b.x, fmaf(-a.y, b.y, acc.x)),
                     fmaf(a.x, b.y, fmaf(a.y, b.x, acc.y)));
}

template<typename F, int... Is>
__device__ __forceinline__ void sf_impl(F&& f, std::integer_sequence<int, Is...>) {
  (f(std::integral_constant<int, Is>{}), ...);
}
template<int N, typename F>
__device__ __forceinline__ void static_for(F&& f) {
  sf_impl(f, std::make_integer_sequence<int, N>{});
}

// ---- compile-time-dispatched state accessors: reg for r<NREG, LDS above ----
template<int r>
__device__ __forceinline__ float2 getamp(const float2 (&s)[NREG], const float2* sst, int tid) {
  if constexpr (r < NREG) return s[r];
  else return sst[(r - NREG) * NTHR + tid];
}
template<int r>
__device__ __forceinline__ void putamp(float2 (&s)[NREG], float2* sst, int tid, float2 v) {
  if constexpr (r < NREG) s[r] = v;
  else sst[(r - NREG) * NTHR + tid] = v;
}

// ---------------------------------------------------------------------------
// One rotation gate. x = tid<<7 | r ; lane = tid[5:0], wave = tid[8:6].
// Element of total parity b: new = U[b][b]*mine + U[b][1-b]*partner.
// pt (thread-bit parity, runtime) folded into cA0..cB1 once per gate.
// IMPORTANT (r3 bug): the reg-bit parity of EACH element is computed
// explicitly (constexpr) — pair elements do NOT always have opposite
// reg-bit parity when Delta spans thread bits (e.g. layer1/3 wire 8).
// ---------------------------------------------------------------------------
template<int D, int Q>
__device__ __forceinline__ void apply_gate(float2 (&s)[NREG], float2* sst, float2* xch,
                                           const float2* utab, int tid) {
  constexpr int DLT   = MK.delta[D][Q];
  constexpr int R     = MK.rowm[D][Q];
  constexpr int dreg  = DLT & (NAMP - 1);
  constexpr int dthr  = DLT >> 7;
  constexpr int dlane = dthr & 63;
  constexpr int dwave = dthr >> 6;

  const int gbase = (D * NQ + Q) * 4;
  const float2 U00 = utab[gbase + 0];
  const float2 U01 = utab[gbase + 1];
  const float2 U10 = utab[gbase + 2];
  const float2 U11 = utab[gbase + 3];
  const int pt = __popc(tid & (R >> 7)) & 1;
  const float2 cA0 = pt ? U11 : U00;
  const float2 cB0 = pt ? U10 : U01;
  const float2 cA1 = pt ? U00 : U11;
  const float2 cB1 = pt ? U01 : U10;

  if constexpr (dthr == 0) {
    // ---- Case A: pair entirely within this thread ----
    static_for<NAMP>([&](auto rc) {
      constexpr int r = decltype(rc)::value;
      constexpr int r2 = r ^ dreg;
      if constexpr (r < r2) {
        constexpr int p0 = cpar(r & R);
        constexpr int p1 = cpar(r2 & R);     // explicit, not assumed opposite
        const float2 a = getamp<r >(s, sst, tid);
        const float2 c = getamp<r2>(s, sst, tid);
        const float2 A0 = p0 ? cA1 : cA0, B0 = p0 ? cB1 : cB0;
        const float2 A1 = p1 ? cA1 : cA0, B1 = p1 ? cB1 : cB0;
        putamp<r >(s, sst, tid, cfma(A0, a, cmul(B0, c)));
        putamp<r2>(s, sst, tid, cfma(A1, c, cmul(B1, a)));
      }
    });
  } else if constexpr (dwave == 0) {
    // ---- Case B: partner in same wave -> shuffles only ----
    if constexpr (dreg == 0) {
      static_for<NAMP>([&](auto rc) {
        constexpr int r = decltype(rc)::value;
        constexpr int p0 = cpar(r & R);
        const float2 m = getamp<r>(s, sst, tid);
        float2 p;
        p.x = __shfl_xor(m.x, dlane);
        p.y = __shfl_xor(m.y, dlane);
        const float2 A0 = p0 ? cA1 : cA0, B0 = p0 ? cB1 : cB0;
        putamp<r>(s, sst, tid, cfma(A0, m, cmul(B0, p)));
      });
    } else {
      static_for<NAMP>([&](auto rc) {
        constexpr int r = decltype(rc)::value;
        constexpr int r2 = r ^ dreg;
        if constexpr (r < r2) {
          constexpr int p0 = cpar(r & R);
          constexpr int p1 = cpar(r2 & R);   // explicit (r3 bug fix)
          const float2 m0 = getamp<r >(s, sst, tid);
          const float2 m1 = getamp<r2>(s, sst, tid);
          float2 p0v, p1v;
          p0v.x = __shfl_xor(m1.x, dlane);  // partner thread's amp r^dreg
          p0v.y = __shfl_xor(m1.y, dlane);
          p1v.x = __shfl_xor(m0.x, dlane);  // partner thread's amp r
          p1v.y = __shfl_xor(m0.y, dlane);
          const float2 A0 = p0 ? cA1 : cA0, B0 = p0 ? cB1 : cB0;
          const float2 A1 = p1 ? cA1 : cA0, B1 = p1 ? cB1 : cB0;
          putamp<r >(s, sst, tid, cfma(A0, m0, cmul(B0, p0v)));
          putamp<r2>(s, sst, tid, cfma(A1, m1, cmul(B1, p1v)));
        }
      });
    }
  } else {
    // ---- Case C: partner in another wave -> barrier-staged via xch ----
    const int ptid = tid ^ dthr;
    constexpr int kx  = dreg >> 4;   // 16-amp chunk XOR
    constexpr int d15 = dreg & 15;
    if constexpr (kx == 0) {
      static_for<8>([&](auto kc) {
        constexpr int k = decltype(kc)::value;
        static_for<16>([&](auto jc) {
          constexpr int j = decltype(jc)::value;
          xch[j * NTHR + tid] = getamp<16 * k + j>(s, sst, tid);
        });
        __syncthreads();
        static_for<16>([&](auto jc) {
          constexpr int j = decltype(jc)::value;
          constexpr int r = 16 * k + j;
          constexpr int p0 = cpar(r & R);
          const float2 m = getamp<r>(s, sst, tid);
          const float2 p = xch[(j ^ d15) * NTHR + ptid];
          const float2 A0 = p0 ? cA1 : cA0, B0 = p0 ? cB1 : cB0;
          putamp<r>(s, sst, tid, cfma(A0, m, cmul(B0, p)));
        });
        __syncthreads();
      });
    } else {
      constexpr int d8 = (dreg >> 3) & 1;
      constexpr int d7 = dreg & 7;
      static_for<8>([&](auto cc) {
        constexpr int c = decltype(cc)::value;
        if constexpr (c < (c ^ kx)) {
          constexpr int c2 = c ^ kx;
          static_for<2>([&](auto hc) {
            constexpr int h  = decltype(hc)::value;
            constexpr int h2 = h ^ d8;
            static_for<8>([&](auto jc) {
              constexpr int j = decltype(jc)::value;
              xch[j * NTHR + tid]       = getamp<16 * c  + 8 * h  + j>(s, sst, tid);
              xch[(8 + j) * NTHR + tid] = getamp<16 * c2 + 8 * h2 + j>(s, sst, tid);
            });
            __syncthreads();
            static_for<8>([&](auto jc) {
              constexpr int j = decltype(jc)::value;
              {
                constexpr int r = 16 * c + 8 * h + j;   // partner in slots 8..15
                constexpr int p0 = cpar(r & R);
                const float2 m = getamp<r>(s, sst, tid);
                const float2 p = xch[(8 + (j ^ d7)) * NTHR + ptid];
                const float2 A0 = p0 ? cA1 : cA0, B0 = p0 ? cB1 : cB0;
                putamp<r>(s, sst, tid, cfma(A0, m, cmul(B0, p)));
              }
              {
                constexpr int r = 16 * c2 + 8 * h2 + j; // partner in slots 0..7
                constexpr int p0 = cpar(r & R);
                const float2 m = getamp<r>(s, sst, tid);
                const float2 p = xch[(j ^ d7) * NTHR + ptid];
                const float2 A0 = p0 ? cA1 : cA0, B0 = p0 ? cB1 : cB0;
                putamp<r>(s, sst, tid, cfma(A0, m, cmul(B0, p)));
              }
            });
            __syncthreads();
          });
        }
      });
    }
  }
}

template<int D, int Q>
__device__ __forceinline__ void apply_all(float2 (&s)[NREG], float2* sst, float2* xch,
                                          const float2* utab, int tid) {
  apply_gate<D, Q>(s, sst, xch, utab, tid);
  if constexpr (Q < NQ - 1) {
    apply_all<D, Q + 1>(s, sst, xch, utab, tid);
  } else if constexpr (D < NDEPTH - 1) {
    apply_all<D + 1, 0>(s, sst, xch, utab, tid);
  }
}

// min-waves = 1: LDS (130 KB) already forces 1 block/CU, so there is no
// occupancy cost to an uncapped VGPR budget — guarantees no spill.
__global__ __launch_bounds__(NTHR, 1) void qsim_kernel(const float* __restrict__ x,
                                                       const float* __restrict__ params,
                                                       float* __restrict__ out) {
  __shared__ float2 sst[NLDS * NTHR];          // 64 KB LDS-resident state
  __shared__ float2 xch[16 * NTHR];            // 64 KB exchange buffer
  __shared__ float2 utab[NDEPTH * NQ * 4];     // 2 KB gate matrices

  const int tid = threadIdx.x;
  const int b = blockIdx.x;

  // ---- per-block gate table: U = RZ(tz) RY(ty) RX(tx) ----
  if (tid < NDEPTH * NQ) {
    const int d = tid / NQ, q = tid % NQ;
    const float a = tanhf(x[b * NQ + q]);
    const float tx = a + params[(d * NQ + q) * 3 + 0];
    const float ty = a + params[(d * NQ + q) * 3 + 1];
    const float tz = a + params[(d * NQ + q) * 3 + 2];
    const float cx = cosf(0.5f * tx), sx = sinf(0.5f * tx);
    const float cy = cosf(0.5f * ty), sy = sinf(0.5f * ty);
    const float cz = cosf(0.5f * tz), sz = sinf(0.5f * tz);
    const float2 m00 = make_float2(cy * cx,  sy * sx);
    const float2 m01 = make_float2(-sy * cx, -cy * sx);
    const float2 m10 = make_float2(sy * cx,  -cy * sx);
    const float2 m11 = make_float2(cy * cx,  -sy * sx);
    const float2 ez  = make_float2(cz, -sz);
    const float2 ezc = make_float2(cz,  sz);
    utab[tid * 4 + 0] = cmul(ez,  m00);
    utab[tid * 4 + 1] = cmul(ez,  m01);
    utab[tid * 4 + 2] = cmul(ezc, m10);
    utab[tid * 4 + 3] = cmul(ezc, m11);
  }

  // ---- state init: |0..0> (amp x=0 lives at tid 0, r 0) ----
  float2 s[NREG];
  static_for<NREG>([&](auto rc) { s[decltype(rc)::value] = make_float2(0.f, 0.f); });
  static_for<NLDS>([&](auto ic) {
    sst[decltype(ic)::value * NTHR + tid] = make_float2(0.f, 0.f);
  });
  if (tid == 0) s[0].x = 1.0f;
  __syncthreads();

  // ---- all 64 rotation gates (CNOTs folded into constexpr masks) ----
  apply_all<0, 0>(s, sst, xch, utab, tid);

  // ---- Z expectations: z_q = sum_x (-1)^{par(x & meas_q)} |s[x]|^2 ----
  float z[NQ];
  static_for<NQ>([&](auto qc) { z[decltype(qc)::value] = 0.f; });
  static_for<NAMP>([&](auto rc) {
    constexpr int r = decltype(rc)::value;
    const float2 v = getamp<r>(s, sst, tid);
    const float pr = v.x * v.x + v.y * v.y;
    static_for<NQ>([&](auto qc) {
      constexpr int q = decltype(qc)::value;
      constexpr bool neg = cpar(r & MK.meas[q]) != 0;
      z[q] = neg ? (z[q] - pr) : (z[q] + pr);
    });
  });
  static_for<NQ>([&](auto qc) {
    constexpr int q = decltype(qc)::value;
    const int ptq = __popc(tid & (MK.meas[q] >> 7)) & 1;
    float v = ptq ? -z[q] : z[q];
    static_for<6>([&](auto ic) {
      constexpr int sh = 32 >> decltype(ic)::value;
      v += __shfl_xor(v, sh);
    });
    z[q] = v;
  });
  __syncthreads();                 // xch free for reuse
  float* red = (float*)xch;
  if ((tid & 63) == 0) {
    const int w = tid >> 6;
    static_for<NQ>([&](auto qc) {
      constexpr int q = decltype(qc)::value;
      red[w * NQ + q] = z[q];
    });
  }
  __syncthreads();
  if (tid < NQ) {
    float acc = 0.f;
#pragma unroll
    for (int w = 0; w < 8; ++w) acc += red[w * NQ + tid];
    out[b * NQ + tid] = acc;
  }
}

extern "C" void kernel_launch(void* const* d_in, const int* in_sizes, int n_in,
                              void* d_out, int out_size, void* d_ws, size_t ws_size,
                              hipStream_t stream) {
  const float* x      = (const float*)d_in[0];
  const float* params = (const float*)d_in[1];
  float* out          = (float*)d_out;
  qsim_kernel<<<dim3(NBATCH), dim3(NTHR), 0, stream>>>(x, params, out);
}

// Round 6
// 1059.363 us; speedup vs baseline: 14.7805x; 1.3217x over previous
//
#include <hip/hip_runtime.h>
#include <cstdint>
#include <utility>

#define NQ 16
#define NDEPTH 4
#define NBATCH 512
#define NTHR 512      // threads per block (8 waves = 2 waves/SIMD, pinned)
#define NAMP 128      // amps per thread (65536 / NTHR)
#define NREG 97       // amps in registers (194 VGPRs; budget 256 via waves_per_eu(2,2))
#define NLDS (NAMP - NREG)   // 31 amps in LDS: 31*512*8 = 124 KB
#define XS 8          // exchange slots: 8*512*8 = 32 KB

// ---------------------------------------------------------------------------
// Compile-time GF(2) tracking of the CNOT ring (mask algebra verified r1/r4,
// passed at absmax 6.1e-5).  Physical index x (16 bits): bit b <-> wire 15-b.
// Rotation on logical wire q at layer d:
//   pair mask  Delta = A^{-1} e_p, parity row R = row_p(A), p = 15-q.
// Layout: x = (tid << 7) | r ; reg = x[6:0], lane = tid[5:0], wave = tid[8:6].
// Enumerated: Case C (wave-crossing) gates all have dreg <= 7.
// ---------------------------------------------------------------------------
struct Masks {
  unsigned short delta[NDEPTH][NQ];
  unsigned short rowm[NDEPTH][NQ];
  unsigned short meas[NQ];
};

constexpr Masks make_masks() {
  Masks m = {};
  unsigned short Arow[NQ] = {};
  unsigned short Ainv[NQ] = {};
  for (int p = 0; p < NQ; ++p) {
    Arow[p] = (unsigned short)(1u << p);
    Ainv[p] = (unsigned short)(1u << p);
  }
  for (int d = 0; d < NDEPTH; ++d) {
    for (int q = 0; q < NQ; ++q) {
      m.delta[d][q] = Ainv[15 - q];
      m.rowm[d][q]  = Arow[15 - q];
    }
    for (int q = 0; q < NQ - 1; ++q) {    // CNOT(q, q+1)
      const int pc = 15 - q, pt = 15 - (q + 1);
      Arow[pt] = (unsigned short)(Arow[pt] ^ Arow[pc]);
      Ainv[pc] = (unsigned short)(Ainv[pc] ^ Ainv[pt]);
    }
    {                                      // CNOT(15, 0)
      const int pc = 0, pt = 15;
      Arow[pt] = (unsigned short)(Arow[pt] ^ Arow[pc]);
      Ainv[pc] = (unsigned short)(Ainv[pc] ^ Ainv[pt]);
    }
  }
  for (int q = 0; q < NQ; ++q) m.meas[q] = Arow[15 - q];
  return m;
}

constexpr Masks MK = make_masks();

constexpr int cpar(int v) {
  int p = 0;
  for (int i = 0; i < 16; ++i) p ^= (v >> i) & 1;
  return p;
}

__device__ __forceinline__ float2 cmul(float2 a, float2 b) {
  return make_float2(a.x * b.x - a.y * b.y, a.x * b.y + a.y * b.x);
}
__device__ __forceinline__ float2 cfma(float2 a, float2 b, float2 acc) {
  return make_float2(fmaf(a.x, b.x, fmaf(-a.y, b.y, acc.x)),
                     fmaf(a.x, b.y, fmaf(a.y, b.x, acc.y)));
}

template<typename F, int... Is>
__device__ __forceinline__ void sf_impl(F&& f, std::integer_sequence<int, Is...>) {
  (f(std::integral_constant<int, Is>{}), ...);
}
template<int N, typename F>
__device__ __forceinline__ void static_for(F&& f) {
  sf_impl(f, std::make_integer_sequence<int, N>{});
}

// ---- compile-time-dispatched state accessors: reg for r<NREG, LDS above ----
template<int r>
__device__ __forceinline__ float2 getamp(const float2 (&s)[NREG], const float2* sst, int tid) {
  if constexpr (r < NREG) return s[r];
  else return sst[(r - NREG) * NTHR + tid];
}
template<int r>
__device__ __forceinline__ void putamp(float2 (&s)[NREG], float2* sst, int tid, float2 v) {
  if constexpr (r < NREG) s[r] = v;
  else sst[(r - NREG) * NTHR + tid] = v;
}

// ---------------------------------------------------------------------------
// One rotation gate. Element of total parity b: new = U[b][b]*mine +
// U[b][1-b]*partner.  pt (thread-bit parity, runtime) folded into cA0..cB1
// once per gate; each element's reg-bit parity is computed EXPLICITLY
// (constexpr) — pair elements need not have opposite reg-bit parity (r3 bug).
// ---------------------------------------------------------------------------
template<int D, int Q>
__device__ __forceinline__ void apply_gate(float2 (&s)[NREG], float2* sst, float2* xch,
                                           const float2* utab, int tid) {
  constexpr int DLT   = MK.delta[D][Q];
  constexpr int R     = MK.rowm[D][Q];
  constexpr int dreg  = DLT & (NAMP - 1);
  constexpr int dthr  = DLT >> 7;
  constexpr int dlane = dthr & 63;
  constexpr int dwave = dthr >> 6;

  const int gbase = (D * NQ + Q) * 4;
  const float2 U00 = utab[gbase + 0];
  const float2 U01 = utab[gbase + 1];
  const float2 U10 = utab[gbase + 2];
  const float2 U11 = utab[gbase + 3];
  const int pt = __popc(tid & (R >> 7)) & 1;
  const float2 cA0 = pt ? U11 : U00;
  const float2 cB0 = pt ? U10 : U01;
  const float2 cA1 = pt ? U00 : U11;
  const float2 cB1 = pt ? U01 : U10;

  if constexpr (dthr == 0) {
    // ---- Case A: pair entirely within this thread ----
    static_for<NAMP>([&](auto rc) {
      constexpr int r = decltype(rc)::value;
      constexpr int r2 = r ^ dreg;
      if constexpr (r < r2) {
        constexpr int p0 = cpar(r & R);
        constexpr int p1 = cpar(r2 & R);     // explicit, not assumed opposite
        const float2 a = getamp<r >(s, sst, tid);
        const float2 c = getamp<r2>(s, sst, tid);
        const float2 A0 = p0 ? cA1 : cA0, B0 = p0 ? cB1 : cB0;
        const float2 A1 = p1 ? cA1 : cA0, B1 = p1 ? cB1 : cB0;
        putamp<r >(s, sst, tid, cfma(A0, a, cmul(B0, c)));
        putamp<r2>(s, sst, tid, cfma(A1, c, cmul(B1, a)));
      }
    });
  } else if constexpr (dwave == 0) {
    // ---- Case B: partner in same wave -> shuffles only ----
    if constexpr (dreg == 0) {
      static_for<NAMP>([&](auto rc) {
        constexpr int r = decltype(rc)::value;
        constexpr int p0 = cpar(r & R);
        const float2 m = getamp<r>(s, sst, tid);
        float2 p;
        p.x = __shfl_xor(m.x, dlane);
        p.y = __shfl_xor(m.y, dlane);
        const float2 A0 = p0 ? cA1 : cA0, B0 = p0 ? cB1 : cB0;
        putamp<r>(s, sst, tid, cfma(A0, m, cmul(B0, p)));
      });
    } else {
      static_for<NAMP>([&](auto rc) {
        constexpr int r = decltype(rc)::value;
        constexpr int r2 = r ^ dreg;
        if constexpr (r < r2) {
          constexpr int p0 = cpar(r & R);
          constexpr int p1 = cpar(r2 & R);
          const float2 m0 = getamp<r >(s, sst, tid);
          const float2 m1 = getamp<r2>(s, sst, tid);
          float2 p0v, p1v;
          p0v.x = __shfl_xor(m1.x, dlane);  // partner thread's amp r^dreg
          p0v.y = __shfl_xor(m1.y, dlane);
          p1v.x = __shfl_xor(m0.x, dlane);  // partner thread's amp r
          p1v.y = __shfl_xor(m0.y, dlane);
          const float2 A0 = p0 ? cA1 : cA0, B0 = p0 ? cB1 : cB0;
          const float2 A1 = p1 ? cA1 : cA0, B1 = p1 ? cB1 : cB0;
          putamp<r >(s, sst, tid, cfma(A0, m0, cmul(B0, p0v)));
          putamp<r2>(s, sst, tid, cfma(A1, m1, cmul(B1, p1v)));
        }
      });
    }
  } else {
    // ---- Case C: partner in another wave -> barrier-staged via xch ----
    const int ptid = tid ^ dthr;
    if constexpr ((dreg >> 3) == 0) {
      // partner amp in the same 8-amp chunk (true for ALL instantiated C gates)
      static_for<NAMP / 8>([&](auto kc) {
        constexpr int k = decltype(kc)::value;
        static_for<8>([&](auto jc) {
          constexpr int j = decltype(jc)::value;
          xch[j * NTHR + tid] = getamp<8 * k + j>(s, sst, tid);
        });
        __syncthreads();
        static_for<8>([&](auto jc) {
          constexpr int j = decltype(jc)::value;
          constexpr int r = 8 * k + j;
          constexpr int p0 = cpar(r & R);
          const float2 m = getamp<r>(s, sst, tid);
          const float2 p = xch[(j ^ dreg) * NTHR + ptid];
          const float2 A0 = p0 ? cA1 : cA0, B0 = p0 ? cB1 : cB0;
          putamp<r>(s, sst, tid, cfma(A0, m, cmul(B0, p)));
        });
        __syncthreads();
      });
    } else {
      // generic chunk-pairing (not instantiated by this circuit; kept correct)
      constexpr int kx = dreg >> 3;
      constexpr int d4 = (dreg >> 2) & 1;
      constexpr int d3 = dreg & 3;
      static_for<NAMP / 8>([&](auto cc) {
        constexpr int c = decltype(cc)::value;
        if constexpr (c < (c ^ kx)) {
          constexpr int c2 = c ^ kx;
          static_for<2>([&](auto hc) {
            constexpr int h  = decltype(hc)::value;
            constexpr int h2 = h ^ d4;
            static_for<4>([&](auto jc) {
              constexpr int j = decltype(jc)::value;
              xch[j * NTHR + tid]       = getamp<8 * c  + 4 * h  + j>(s, sst, tid);
              xch[(4 + j) * NTHR + tid] = getamp<8 * c2 + 4 * h2 + j>(s, sst, tid);
            });
            __syncthreads();
            static_for<4>([&](auto jc) {
              constexpr int j = decltype(jc)::value;
              {
                constexpr int r = 8 * c + 4 * h + j;    // partner in slots 4..7
                constexpr int p0 = cpar(r & R);
                const float2 m = getamp<r>(s, sst, tid);
                const float2 p = xch[(4 + (j ^ d3)) * NTHR + ptid];
                const float2 A0 = p0 ? cA1 : cA0, B0 = p0 ? cB1 : cB0;
                putamp<r>(s, sst, tid, cfma(A0, m, cmul(B0, p)));
              }
              {
                constexpr int r = 8 * c2 + 4 * h2 + j;  // partner in slots 0..3
                constexpr int p0 = cpar(r & R);
                const float2 m = getamp<r>(s, sst, tid);
                const float2 p = xch[((j ^ d3)) * NTHR + ptid];
                const float2 A0 = p0 ? cA1 : cA0, B0 = p0 ? cB1 : cB0;
                putamp<r>(s, sst, tid, cfma(A0, m, cmul(B0, p)));
              }
            });
            __syncthreads();
          });
        }
      });
    }
  }
}

template<int D, int Q>
__device__ __forceinline__ void apply_all(float2 (&s)[NREG], float2* sst, float2* xch,
                                          const float2* utab, int tid) {
  apply_gate<D, Q>(s, sst, xch, utab, tid);
  if constexpr (Q < NQ - 1) {
    apply_all<D, Q + 1>(s, sst, xch, utab, tid);
  } else if constexpr (D < NDEPTH - 1) {
    apply_all<D + 1, 0>(s, sst, xch, utab, tid);
  }
}

// 8-wave block, LDS 158 KB -> 1 block/CU -> exactly 2 waves/SIMD.
// amdgpu_waves_per_eu(2,2) pins the allocator budget to 512/2 = 256 VGPRs
// (launch_bounds' 2nd arg is only a MINIMUM promise and the default
// occupancy heuristic under-allocates -> r4's spill).
__global__ __launch_bounds__(NTHR)
__attribute__((amdgpu_waves_per_eu(2, 2)))
void qsim_kernel(const float* __restrict__ x,
                 const float* __restrict__ params,
                 float* __restrict__ out) {
  __shared__ float2 sst[NLDS * NTHR];          // 124 KB LDS-resident state
  __shared__ float2 xch[XS * NTHR];            // 32 KB exchange buffer
  __shared__ float2 utab[NDEPTH * NQ * 4];     // 2 KB gate matrices

  const int tid = threadIdx.x;
  const int b = blockIdx.x;

  // ---- per-block gate table: U = RZ(tz) RY(ty) RX(tx) ----
  if (tid < NDEPTH * NQ) {
    const int d = tid / NQ, q = tid % NQ;
    const float a = tanhf(x[b * NQ + q]);
    const float tx = a + params[(d * NQ + q) * 3 + 0];
    const float ty = a + params[(d * NQ + q) * 3 + 1];
    const float tz = a + params[(d * NQ + q) * 3 + 2];
    const float cx = cosf(0.5f * tx), sx = sinf(0.5f * tx);
    const float cy = cosf(0.5f * ty), sy = sinf(0.5f * ty);
    const float cz = cosf(0.5f * tz), sz = sinf(0.5f * tz);
    const float2 m00 = make_float2(cy * cx,  sy * sx);
    const float2 m01 = make_float2(-sy * cx, -cy * sx);
    const float2 m10 = make_float2(sy * cx,  -cy * sx);
    const float2 m11 = make_float2(cy * cx,  -sy * sx);
    const float2 ez  = make_float2(cz, -sz);
    const float2 ezc = make_float2(cz,  sz);
    utab[tid * 4 + 0] = cmul(ez,  m00);
    utab[tid * 4 + 1] = cmul(ez,  m01);
    utab[tid * 4 + 2] = cmul(ezc, m10);
    utab[tid * 4 + 3] = cmul(ezc, m11);
  }

  // ---- state init: |0..0> (amp x=0 lives at tid 0, r 0) ----
  float2 s[NREG];
  static_for<NREG>([&](auto rc) { s[decltype(rc)::value] = make_float2(0.f, 0.f); });
  static_for<NLDS>([&](auto ic) {
    sst[decltype(ic)::value * NTHR + tid] = make_float2(0.f, 0.f);
  });
  if (tid == 0) s[0].x = 1.0f;
  __syncthreads();

  // ---- all 64 rotation gates (CNOTs folded into constexpr masks) ----
  apply_all<0, 0>(s, sst, xch, utab, tid);

  // ---- Z expectations: z_q = sum_x (-1)^{par(x & meas_q)} |s[x]|^2 ----
  float z[NQ];
  static_for<NQ>([&](auto qc) { z[decltype(qc)::value] = 0.f; });
  static_for<NAMP>([&](auto rc) {
    constexpr int r = decltype(rc)::value;
    const float2 v = getamp<r>(s, sst, tid);
    const float pr = v.x * v.x + v.y * v.y;
    static_for<NQ>([&](auto qc) {
      constexpr int q = decltype(qc)::value;
      constexpr bool neg = cpar(r & MK.meas[q]) != 0;
      z[q] = neg ? (z[q] - pr) : (z[q] + pr);
    });
  });
  static_for<NQ>([&](auto qc) {
    constexpr int q = decltype(qc)::value;
    const int ptq = __popc(tid & (MK.meas[q] >> 7)) & 1;
    float v = ptq ? -z[q] : z[q];
    static_for<6>([&](auto ic) {
      constexpr int sh = 32 >> decltype(ic)::value;
      v += __shfl_xor(v, sh);
    });
    z[q] = v;
  });
  __syncthreads();                 // xch free for reuse
  float* red = (float*)xch;
  if ((tid & 63) == 0) {
    const int w = tid >> 6;        // 8 waves
    static_for<NQ>([&](auto qc) {
      constexpr int q = decltype(qc)::value;
      red[w * NQ + q] = z[q];
    });
  }
  __syncthreads();
  if (tid < NQ) {
    float acc = 0.f;
#pragma unroll
    for (int w = 0; w < 8; ++w) acc += red[w * NQ + tid];
    out[b * NQ + tid] = acc;
  }
}

extern "C" void kernel_launch(void* const* d_in, const int* in_sizes, int n_in,
                              void* d_out, int out_size, void* d_ws, size_t ws_size,
                              hipStream_t stream) {
  const float* x      = (const float*)d_in[0];
  const float* params = (const float*)d_in[1];
  float* out          = (float*)d_out;
  qsim_kernel<<<dim3(NBATCH), dim3(NTHR), 0, stream>>>(x, params, out);
}

// Round 7
// 1007.020 us; speedup vs baseline: 15.5488x; 1.0520x over previous
//
#include <hip/hip_runtime.h>
#include <cstdint>
#include <utility>

#define NQ 16
#define NDEPTH 4
#define NBATCH 512
#define NTHR 512      // threads per block (8 waves = 2 waves/SIMD, pinned)
#define NAMP 128      // amps per thread (65536 / NTHR)
#define NREG 93       // amps in registers (186 VGPRs; budget 256 via waves_per_eu(2,2))
#define NLDS (NAMP - NREG)   // 35 amps in LDS: 35*512*8 = 140 KB
#define XS 4          // exchange slots: 4*512*8 = 16 KB

// ---------------------------------------------------------------------------
// Compile-time GF(2) tracking of the CNOT ring (mask algebra verified r1/r4/r6,
// passed at absmax 6.1e-5).  Physical index x (16 bits): bit b <-> wire 15-b.
// Rotation on logical wire q at layer d:
//   pair mask  Delta = A^{-1} e_p, parity row R = row_p(A), p = 15-q.
// Layout: x = (tid << 7) | r ; reg = x[6:0], lane = tid[5:0], wave = tid[8:6].
// Enumerated C-gate (wave-crossing) dregs: {0 (x12), 1 (x3), 2, 3, 7}.
// ---------------------------------------------------------------------------
struct Masks {
  unsigned short delta[NDEPTH][NQ];
  unsigned short rowm[NDEPTH][NQ];
  unsigned short meas[NQ];
};

constexpr Masks make_masks() {
  Masks m = {};
  unsigned short Arow[NQ] = {};
  unsigned short Ainv[NQ] = {};
  for (int p = 0; p < NQ; ++p) {
    Arow[p] = (unsigned short)(1u << p);
    Ainv[p] = (unsigned short)(1u << p);
  }
  for (int d = 0; d < NDEPTH; ++d) {
    for (int q = 0; q < NQ; ++q) {
      m.delta[d][q] = Ainv[15 - q];
      m.rowm[d][q]  = Arow[15 - q];
    }
    for (int q = 0; q < NQ - 1; ++q) {    // CNOT(q, q+1)
      const int pc = 15 - q, pt = 15 - (q + 1);
      Arow[pt] = (unsigned short)(Arow[pt] ^ Arow[pc]);
      Ainv[pc] = (unsigned short)(Ainv[pc] ^ Ainv[pt]);
    }
    {                                      // CNOT(15, 0)
      const int pc = 0, pt = 15;
      Arow[pt] = (unsigned short)(Arow[pt] ^ Arow[pc]);
      Ainv[pc] = (unsigned short)(Ainv[pc] ^ Ainv[pt]);
    }
  }
  for (int q = 0; q < NQ; ++q) m.meas[q] = Arow[15 - q];
  return m;
}

constexpr Masks MK = make_masks();

constexpr int cpar(int v) {
  int p = 0;
  for (int i = 0; i < 16; ++i) p ^= (v >> i) & 1;
  return p;
}

// block of 16 amps [16*blk, 16*blk+16) contains only register-resident pair
// work for this dreg? (fence placement: only cap scheduling in pure-VGPR code)
constexpr bool blk_pure_pairs(int blk, int dreg) {
  for (int r = 16 * blk; r < 16 * blk + 16; ++r) {
    const int r2 = r ^ dreg;
    if (r < r2 && (r >= NREG || r2 >= NREG)) return false;
  }
  return true;
}

__device__ __forceinline__ float2 cmul(float2 a, float2 b) {
  return make_float2(a.x * b.x - a.y * b.y, a.x * b.y + a.y * b.x);
}
__device__ __forceinline__ float2 cfma(float2 a, float2 b, float2 acc) {
  return make_float2(fmaf(a.x, b.x, fmaf(-a.y, b.y, acc.x)),
                     fmaf(a.x, b.y, fmaf(a.y, b.x, acc.y)));
}

template<typename F, int... Is>
__device__ __forceinline__ void sf_impl(F&& f, std::integer_sequence<int, Is...>) {
  (f(std::integral_constant<int, Is>{}), ...);
}
template<int N, typename F>
__device__ __forceinline__ void static_for(F&& f) {
  sf_impl(f, std::make_integer_sequence<int, N>{});
}

// ---- compile-time-dispatched state accessors: reg for r<NREG, LDS above ----
template<int r>
__device__ __forceinline__ float2 getamp(const float2 (&s)[NREG], const float2* sst, int tid) {
  if constexpr (r < NREG) return s[r];
  else return sst[(r - NREG) * NTHR + tid];
}
template<int r>
__device__ __forceinline__ void putamp(float2 (&s)[NREG], float2* sst, int tid, float2 v) {
  if constexpr (r < NREG) s[r] = v;
  else sst[(r - NREG) * NTHR + tid] = v;
}

// ---------------------------------------------------------------------------
// One rotation gate. Element of total parity b: new = U[b][b]*mine +
// U[b][1-b]*partner.  pt (thread-bit parity, runtime) folded into cA0..cB1
// once per gate; each element's reg-bit parity is computed EXPLICITLY
// (constexpr) — pair elements need not have opposite reg-bit parity (r3 bug).
// ---------------------------------------------------------------------------
template<int D, int Q>
__device__ __forceinline__ void apply_gate(float2 (&s)[NREG], float2* sst, float2* xch,
                                           const float2* utab, int tid) {
  constexpr int DLT   = MK.delta[D][Q];
  constexpr int R     = MK.rowm[D][Q];
  constexpr int dreg  = DLT & (NAMP - 1);
  constexpr int dthr  = DLT >> 7;
  constexpr int dlane = dthr & 63;
  constexpr int dwave = dthr >> 6;

  const int gbase = (D * NQ + Q) * 4;
  const float2 U00 = utab[gbase + 0];
  const float2 U01 = utab[gbase + 1];
  const float2 U10 = utab[gbase + 2];
  const float2 U11 = utab[gbase + 3];
  const int pt = __popc(tid & (R >> 7)) & 1;
  const float2 cA0 = pt ? U11 : U00;
  const float2 cB0 = pt ? U10 : U01;
  const float2 cA1 = pt ? U00 : U11;
  const float2 cB1 = pt ? U01 : U10;

  if constexpr (dthr == 0) {
    // ---- Case A: pair entirely within this thread ----
    static_for<8>([&](auto bc) {
      constexpr int BB = decltype(bc)::value;
      static_for<16>([&](auto jc) {
        constexpr int r = 16 * BB + decltype(jc)::value;
        constexpr int r2 = r ^ dreg;
        if constexpr (r < r2) {
          constexpr int p0 = cpar(r & R);
          constexpr int p1 = cpar(r2 & R);   // explicit, not assumed opposite
          const float2 a = getamp<r >(s, sst, tid);
          const float2 c = getamp<r2>(s, sst, tid);
          const float2 A0 = p0 ? cA1 : cA0, B0 = p0 ? cB1 : cB0;
          const float2 A1 = p1 ? cA1 : cA0, B1 = p1 ? cB1 : cB0;
          putamp<r >(s, sst, tid, cfma(A0, a, cmul(B0, c)));
          putamp<r2>(s, sst, tid, cfma(A1, c, cmul(B1, a)));
        }
      });
      if constexpr (blk_pure_pairs(BB, dreg)) __builtin_amdgcn_sched_barrier(0);
    });
  } else if constexpr (dwave == 0) {
    // ---- Case B: partner in same wave -> shuffles only ----
    if constexpr (dreg == 0) {
      static_for<8>([&](auto bc) {
        constexpr int BB = decltype(bc)::value;
        static_for<16>([&](auto jc) {
          constexpr int r = 16 * BB + decltype(jc)::value;
          constexpr int p0 = cpar(r & R);
          const float2 m = getamp<r>(s, sst, tid);
          float2 p;
          p.x = __shfl_xor(m.x, dlane);
          p.y = __shfl_xor(m.y, dlane);
          const float2 A0 = p0 ? cA1 : cA0, B0 = p0 ? cB1 : cB0;
          putamp<r>(s, sst, tid, cfma(A0, m, cmul(B0, p)));
        });
        if constexpr (16 * BB + 15 < NREG) __builtin_amdgcn_sched_barrier(0);
      });
    } else {
      static_for<8>([&](auto bc) {
        constexpr int BB = decltype(bc)::value;
        static_for<16>([&](auto jc) {
          constexpr int r = 16 * BB + decltype(jc)::value;
          constexpr int r2 = r ^ dreg;
          if constexpr (r < r2) {
            constexpr int p0 = cpar(r & R);
            constexpr int p1 = cpar(r2 & R);
            const float2 m0 = getamp<r >(s, sst, tid);
            const float2 m1 = getamp<r2>(s, sst, tid);
            float2 p0v, p1v;
            p0v.x = __shfl_xor(m1.x, dlane);  // partner thread's amp r^dreg
            p0v.y = __shfl_xor(m1.y, dlane);
            p1v.x = __shfl_xor(m0.x, dlane);  // partner thread's amp r
            p1v.y = __shfl_xor(m0.y, dlane);
            const float2 A0 = p0 ? cA1 : cA0, B0 = p0 ? cB1 : cB0;
            const float2 A1 = p1 ? cA1 : cA0, B1 = p1 ? cB1 : cB0;
            putamp<r >(s, sst, tid, cfma(A0, m0, cmul(B0, p0v)));
            putamp<r2>(s, sst, tid, cfma(A1, m1, cmul(B1, p1v)));
          }
        });
        if constexpr (blk_pure_pairs(BB, dreg)) __builtin_amdgcn_sched_barrier(0);
      });
    }
  } else {
    // ---- Case C: partner in another wave -> barrier-staged via xch ----
    const int ptid = tid ^ dthr;
    if constexpr (dreg < XS) {
      // partner amp within the same 4-amp chunk (dreg in {0,1,2,3})
      static_for<NAMP / XS>([&](auto kc) {
        constexpr int k = decltype(kc)::value;
        static_for<XS>([&](auto jc) {
          constexpr int j = decltype(jc)::value;
          xch[j * NTHR + tid] = getamp<XS * k + j>(s, sst, tid);
        });
        __syncthreads();
        static_for<XS>([&](auto jc) {
          constexpr int j = decltype(jc)::value;
          constexpr int r = XS * k + j;
          constexpr int p0 = cpar(r & R);
          const float2 m = getamp<r>(s, sst, tid);
          const float2 p = xch[(j ^ dreg) * NTHR + ptid];
          const float2 A0 = p0 ? cA1 : cA0, B0 = p0 ? cB1 : cB0;
          putamp<r>(s, sst, tid, cfma(A0, m, cmul(B0, p)));
        });
        __syncthreads();
      });
    } else {
      // chunk-pair path (dreg >= 4; instantiated only for dreg=7):
      // pairs chunk c with c2 = c^kx; partner of (c,j) is (c2, j^dj) at ptid.
      constexpr int kx = dreg >> 2;   // chunk XOR  (>=1 here)
      constexpr int dj = dreg & 3;    // within-chunk offset
      static_for<NAMP / XS>([&](auto cc) {
        constexpr int c = decltype(cc)::value;
        if constexpr (c < (c ^ kx)) {
          constexpr int c2 = c ^ kx;
          // stage chunk c (old)
          static_for<XS>([&](auto jc) {
            constexpr int j = decltype(jc)::value;
            xch[j * NTHR + tid] = getamp<XS * c + j>(s, sst, tid);
          });
          __syncthreads();
          // compute chunk c2's new values into temps (do NOT commit yet)
          float2 t0, t1, t2, t3;
          {
            constexpr int r = XS * c2 + 0; constexpr int p0 = cpar(r & R);
            const float2 m = getamp<r>(s, sst, tid);
            const float2 p = xch[(0 ^ dj) * NTHR + ptid];
            t0 = cfma(p0 ? cA1 : cA0, m, cmul(p0 ? cB1 : cB0, p));
          }
          {
            constexpr int r = XS * c2 + 1; constexpr int p0 = cpar(r & R);
            const float2 m = getamp<r>(s, sst, tid);
            const float2 p = xch[(1 ^ dj) * NTHR + ptid];
            t1 = cfma(p0 ? cA1 : cA0, m, cmul(p0 ? cB1 : cB0, p));
          }
          {
            constexpr int r = XS * c2 + 2; constexpr int p0 = cpar(r & R);
            const float2 m = getamp<r>(s, sst, tid);
            const float2 p = xch[(2 ^ dj) * NTHR + ptid];
            t2 = cfma(p0 ? cA1 : cA0, m, cmul(p0 ? cB1 : cB0, p));
          }
          {
            constexpr int r = XS * c2 + 3; constexpr int p0 = cpar(r & R);
            const float2 m = getamp<r>(s, sst, tid);
            const float2 p = xch[(3 ^ dj) * NTHR + ptid];
            t3 = cfma(p0 ? cA1 : cA0, m, cmul(p0 ? cB1 : cB0, p));
          }
          __syncthreads();
          // stage chunk c2 (still-old values; temps not committed)
          static_for<XS>([&](auto jc) {
            constexpr int j = decltype(jc)::value;
            xch[j * NTHR + tid] = getamp<XS * c2 + j>(s, sst, tid);
          });
          __syncthreads();
          // commit chunk c using staged old c2, then commit temps to c2
          static_for<XS>([&](auto jc) {
            constexpr int j = decltype(jc)::value;
            constexpr int r = XS * c + j;
            constexpr int p0 = cpar(r & R);
            const float2 m = getamp<r>(s, sst, tid);
            const float2 p = xch[(j ^ dj) * NTHR + ptid];
            const float2 A0 = p0 ? cA1 : cA0, B0 = p0 ? cB1 : cB0;
            putamp<r>(s, sst, tid, cfma(A0, m, cmul(B0, p)));
          });
          putamp<XS * c2 + 0>(s, sst, tid, t0);
          putamp<XS * c2 + 1>(s, sst, tid, t1);
          putamp<XS * c2 + 2>(s, sst, tid, t2);
          putamp<XS * c2 + 3>(s, sst, tid, t3);
          __syncthreads();
        }
      });
    }
  }
}

template<int D, int Q>
__device__ __forceinline__ void apply_all(float2 (&s)[NREG], float2* sst, float2* xch,
                                          const float2* utab, int tid) {
  apply_gate<D, Q>(s, sst, xch, utab, tid);
  __builtin_amdgcn_sched_barrier(0);   // no cross-gate scheduling overlap
  if constexpr (Q < NQ - 1) {
    apply_all<D, Q + 1>(s, sst, xch, utab, tid);
  } else if constexpr (D < NDEPTH - 1) {
    apply_all<D + 1, 0>(s, sst, xch, utab, tid);
  }
}

// 8-wave block, LDS 158 KB -> 1 block/CU -> exactly 2 waves/SIMD.
// amdgpu_waves_per_eu(2,2) pins the allocator budget to 512/2 = 256 VGPRs.
__global__ __launch_bounds__(NTHR)
__attribute__((amdgpu_waves_per_eu(2, 2)))
void qsim_kernel(const float* __restrict__ x,
                 const float* __restrict__ params,
                 float* __restrict__ out) {
  __shared__ float2 sst[NLDS * NTHR];          // 140 KB LDS-resident state
  __shared__ float2 xch[XS * NTHR];            // 16 KB exchange buffer
  __shared__ float2 utab[NDEPTH * NQ * 4];     // 2 KB gate matrices

  const int tid = threadIdx.x;
  const int b = blockIdx.x;

  // ---- per-block gate table: U = RZ(tz) RY(ty) RX(tx) ----
  if (tid < NDEPTH * NQ) {
    const int d = tid / NQ, q = tid % NQ;
    const float a = tanhf(x[b * NQ + q]);
    const float tx = a + params[(d * NQ + q) * 3 + 0];
    const float ty = a + params[(d * NQ + q) * 3 + 1];
    const float tz = a + params[(d * NQ + q) * 3 + 2];
    const float cx = cosf(0.5f * tx), sx = sinf(0.5f * tx);
    const float cy = cosf(0.5f * ty), sy = sinf(0.5f * ty);
    const float cz = cosf(0.5f * tz), sz = sinf(0.5f * tz);
    const float2 m00 = make_float2(cy * cx,  sy * sx);
    const float2 m01 = make_float2(-sy * cx, -cy * sx);
    const float2 m10 = make_float2(sy * cx,  -cy * sx);
    const float2 m11 = make_float2(cy * cx,  -sy * sx);
    const float2 ez  = make_float2(cz, -sz);
    const float2 ezc = make_float2(cz,  sz);
    utab[tid * 4 + 0] = cmul(ez,  m00);
    utab[tid * 4 + 1] = cmul(ez,  m01);
    utab[tid * 4 + 2] = cmul(ezc, m10);
    utab[tid * 4 + 3] = cmul(ezc, m11);
  }

  // ---- state init: |0..0> (amp x=0 lives at tid 0, r 0) ----
  float2 s[NREG];
  static_for<NREG>([&](auto rc) { s[decltype(rc)::value] = make_float2(0.f, 0.f); });
  static_for<NLDS>([&](auto ic) {
    sst[decltype(ic)::value * NTHR + tid] = make_float2(0.f, 0.f);
  });
  if (tid == 0) s[0].x = 1.0f;
  __syncthreads();

  // ---- all 64 rotation gates (CNOTs folded into constexpr masks) ----
  apply_all<0, 0>(s, sst, xch, utab, tid);

  // ---- Z expectations, two passes of 8 to cap register pressure ----
  __syncthreads();                 // xch free for reuse as reduction buffer
  float* red = (float*)xch;
  static_for<2>([&](auto hc) {
    constexpr int H = decltype(hc)::value;
    float z[8];
    static_for<8>([&](auto qc) { z[decltype(qc)::value] = 0.f; });
    static_for<NAMP>([&](auto rc) {
      constexpr int r = decltype(rc)::value;
      const float2 v = getamp<r>(s, sst, tid);
      const float pr = v.x * v.x + v.y * v.y;
      static_for<8>([&](auto qc) {
        constexpr int qq = decltype(qc)::value;
        constexpr int q = 8 * H + qq;
        constexpr bool neg = cpar(r & MK.meas[q]) != 0;
        z[qq] = neg ? (z[qq] - pr) : (z[qq] + pr);
      });
    });
    static_for<8>([&](auto qc) {
      constexpr int qq = decltype(qc)::value;
      constexpr int q = 8 * H + qq;
      const int ptq = __popc(tid & (MK.meas[q] >> 7)) & 1;
      float v = ptq ? -z[qq] : z[qq];
      static_for<6>([&](auto ic) {
        constexpr int sh = 32 >> decltype(ic)::value;
        v += __shfl_xor(v, sh);
      });
      z[qq] = v;
    });
    if ((tid & 63) == 0) {
      const int w = tid >> 6;      // 8 waves
      static_for<8>([&](auto qc) {
        constexpr int qq = decltype(qc)::value;
        red[w * 8 + qq] = z[qq];
      });
    }
    __syncthreads();
    if (tid < 8) {
      float acc = 0.f;
#pragma unroll
      for (int w = 0; w < 8; ++w) acc += red[w * 8 + tid];
      out[b * NQ + 8 * H + tid] = acc;
    }
    __syncthreads();
  });
}

extern "C" void kernel_launch(void* const* d_in, const int* in_sizes, int n_in,
                              void* d_out, int out_size, void* d_ws, size_t ws_size,
                              hipStream_t stream) {
  const float* x      = (const float*)d_in[0];
  const float* params = (const float*)d_in[1];
  float* out          = (float*)d_out;
  qsim_kernel<<<dim3(NBATCH), dim3(NTHR), 0, stream>>>(x, params, out);
}

// Round 8
// 855.805 us; speedup vs baseline: 18.2962x; 1.1767x over previous
//
#include <hip/hip_runtime.h>
#include <cstdint>
#include <utility>

#define NQ 16
#define NDEPTH 4
#define NBATCH 512
#define NTHR 512      // threads per block (8 waves = 2 waves/SIMD, pinned)
#define NAMP 128      // amps per thread (65536 / NTHR)
#define NREG 93       // amps in registers (186 VGPRs)
#define NLDS (NAMP - NREG)   // 35 amps in LDS: 35*512*8 = 140 KB
#define XS 4          // exchange slots: 4*512*8 = 16 KB

typedef float vf2 __attribute__((ext_vector_type(2)));

// ---------------------------------------------------------------------------
// Compile-time GF(2) tracking of the CNOT ring (mask algebra verified r1/r4/r7,
// passed at absmax 6.1e-5).  Physical index x (16 bits): bit b <-> wire 15-b.
// Rotation on logical wire q at layer d:
//   pair mask  Delta = A^{-1} e_p, parity row R = row_p(A), p = 15-q.
// Layout: x = (tid << 7) | r ; reg = x[6:0], lane = tid[5:0], wave = tid[8:6].
// Enumerated C-gate (wave-crossing) dregs: {0, 1, 2, 3, 7}.
// ---------------------------------------------------------------------------
struct Masks {
  unsigned short delta[NDEPTH][NQ];
  unsigned short rowm[NDEPTH][NQ];
  unsigned short meas[NQ];
};

constexpr Masks make_masks() {
  Masks m = {};
  unsigned short Arow[NQ] = {};
  unsigned short Ainv[NQ] = {};
  for (int p = 0; p < NQ; ++p) {
    Arow[p] = (unsigned short)(1u << p);
    Ainv[p] = (unsigned short)(1u << p);
  }
  for (int d = 0; d < NDEPTH; ++d) {
    for (int q = 0; q < NQ; ++q) {
      m.delta[d][q] = Ainv[15 - q];
      m.rowm[d][q]  = Arow[15 - q];
    }
    for (int q = 0; q < NQ - 1; ++q) {    // CNOT(q, q+1)
      const int pc = 15 - q, pt = 15 - (q + 1);
      Arow[pt] = (unsigned short)(Arow[pt] ^ Arow[pc]);
      Ainv[pc] = (unsigned short)(Ainv[pc] ^ Ainv[pt]);
    }
    {                                      // CNOT(15, 0)
      const int pc = 0, pt = 15;
      Arow[pt] = (unsigned short)(Arow[pt] ^ Arow[pc]);
      Ainv[pc] = (unsigned short)(Ainv[pc] ^ Ainv[pt]);
    }
  }
  for (int q = 0; q < NQ; ++q) m.meas[q] = Arow[15 - q];
  return m;
}

constexpr Masks MK = make_masks();

constexpr int cpar(int v) {
  int p = 0;
  for (int i = 0; i < 16; ++i) p ^= (v >> i) & 1;
  return p;
}

// block of 16 amps contains only register-resident pair work for this dreg?
constexpr bool blk_pure_pairs(int blk, int dreg) {
  for (int r = 16 * blk; r < 16 * blk + 16; ++r) {
    const int r2 = r ^ dreg;
    if (r < r2 && (r >= NREG || r2 >= NREG)) return false;
  }
  return true;
}

template<typename F, int... Is>
__device__ __forceinline__ void sf_impl(F&& f, std::integer_sequence<int, Is...>) {
  (f(std::integral_constant<int, Is>{}), ...);
}
template<int N, typename F>
__device__ __forceinline__ void static_for(F&& f) {
  sf_impl(f, std::make_integer_sequence<int, N>{});
}

__device__ __forceinline__ vf2 swap2(vf2 v) {
  return __builtin_shufflevector(v, v, 1, 0);
}
// new = A*m + B*p  (complex), coeffs pre-expanded: Arr=(A.re,A.re),
// Ain=(-A.im,A.im), etc.  4 packed ops (v_pk_mul/fma_f32).
__device__ __forceinline__ vf2 upd(vf2 Arr, vf2 Ain, vf2 Brr, vf2 Bin,
                                   vf2 m, vf2 p) {
  vf2 t = Arr * m;
  t = __builtin_elementwise_fma(Ain, swap2(m), t);
  t = __builtin_elementwise_fma(Brr, p, t);
  t = __builtin_elementwise_fma(Bin, swap2(p), t);
  return t;
}

// ---- compile-time-dispatched state accessors: reg for r<NREG, LDS above ----
template<int r>
__device__ __forceinline__ vf2 getamp(const vf2 (&s)[NREG], const vf2* sst, int tid) {
  if constexpr (r < NREG) return s[r];
  else return sst[(r - NREG) * NTHR + tid];
}
template<int r>
__device__ __forceinline__ void putamp(vf2 (&s)[NREG], vf2* sst, int tid, vf2 v) {
  if constexpr (r < NREG) s[r] = v;
  else sst[(r - NREG) * NTHR + tid] = v;
}

// ---------------------------------------------------------------------------
// One rotation gate.  Element of total parity b (= constexpr reg-parity ^
// runtime thread-parity pt): new = U[b][b]*mine + U[b][1-b]*partner.
// Coefficients come pre-expanded from LDS: utab[gate*8 + set*4 + {Arr,Ain,
// Brr,Bin}], set chosen by pt via the LDS address (no selects).
// ---------------------------------------------------------------------------
template<int D, int Q>
__device__ __forceinline__ void apply_gate(vf2 (&s)[NREG], vf2* sst, vf2* xch,
                                           const vf2* utab, int tid) {
  constexpr int DLT   = MK.delta[D][Q];
  constexpr int R     = MK.rowm[D][Q];
  constexpr int dreg  = DLT & (NAMP - 1);
  constexpr int dthr  = DLT >> 7;
  constexpr int dlane = dthr & 63;
  constexpr int dwave = dthr >> 6;

  const int pt = __popc(tid & (R >> 7)) & 1;
  const int cbase = (D * NQ + Q) * 8;
  const int o0 = pt << 2;                 // set for reg-parity 0
  const int o1 = 4 - o0;                  // set for reg-parity 1
  const vf2 A0rr = utab[cbase + o0 + 0], A0in = utab[cbase + o0 + 1];
  const vf2 B0rr = utab[cbase + o0 + 2], B0in = utab[cbase + o0 + 3];
  const vf2 A1rr = utab[cbase + o1 + 0], A1in = utab[cbase + o1 + 1];
  const vf2 B1rr = utab[cbase + o1 + 2], B1in = utab[cbase + o1 + 3];

  if constexpr (dthr == 0) {
    // ---- Case A: pair entirely within this thread ----
    static_for<8>([&](auto bc) {
      constexpr int BB = decltype(bc)::value;
      static_for<16>([&](auto jc) {
        constexpr int r = 16 * BB + decltype(jc)::value;
        constexpr int r2 = r ^ dreg;
        if constexpr (r < r2) {
          constexpr int p0 = cpar(r & R);
          constexpr int p1 = cpar(r2 & R);   // explicit (r3 lesson)
          const vf2 a = getamp<r >(s, sst, tid);
          const vf2 c = getamp<r2>(s, sst, tid);
          const vf2 n0 = p0 ? upd(A1rr, A1in, B1rr, B1in, a, c)
                             : upd(A0rr, A0in, B0rr, B0in, a, c);
          const vf2 n1 = p1 ? upd(A1rr, A1in, B1rr, B1in, c, a)
                             : upd(A0rr, A0in, B0rr, B0in, c, a);
          putamp<r >(s, sst, tid, n0);
          putamp<r2>(s, sst, tid, n1);
        }
      });
      if constexpr (blk_pure_pairs(BB, dreg)) __builtin_amdgcn_sched_barrier(0);
    });
  } else if constexpr (dwave == 0) {
    // ---- Case B: partner in same wave -> shuffles only ----
    if constexpr (dreg == 0) {
      static_for<8>([&](auto bc) {
        constexpr int BB = decltype(bc)::value;
        static_for<16>([&](auto jc) {
          constexpr int r = 16 * BB + decltype(jc)::value;
          constexpr int p0 = cpar(r & R);
          const vf2 m = getamp<r>(s, sst, tid);
          vf2 p;
          p.x = __shfl_xor(m.x, dlane);
          p.y = __shfl_xor(m.y, dlane);
          const vf2 n = p0 ? upd(A1rr, A1in, B1rr, B1in, m, p)
                            : upd(A0rr, A0in, B0rr, B0in, m, p);
          putamp<r>(s, sst, tid, n);
        });
        if constexpr (16 * BB + 15 < NREG) __builtin_amdgcn_sched_barrier(0);
      });
    } else {
      static_for<8>([&](auto bc) {
        constexpr int BB = decltype(bc)::value;
        static_for<16>([&](auto jc) {
          constexpr int r = 16 * BB + decltype(jc)::value;
          constexpr int r2 = r ^ dreg;
          if constexpr (r < r2) {
            constexpr int p0 = cpar(r & R);
            constexpr int p1 = cpar(r2 & R);
            const vf2 m0 = getamp<r >(s, sst, tid);
            const vf2 m1 = getamp<r2>(s, sst, tid);
            vf2 p0v, p1v;
            p0v.x = __shfl_xor(m1.x, dlane);  // partner's amp r^dreg
            p0v.y = __shfl_xor(m1.y, dlane);
            p1v.x = __shfl_xor(m0.x, dlane);  // partner's amp r
            p1v.y = __shfl_xor(m0.y, dlane);
            const vf2 n0 = p0 ? upd(A1rr, A1in, B1rr, B1in, m0, p0v)
                               : upd(A0rr, A0in, B0rr, B0in, m0, p0v);
            const vf2 n1 = p1 ? upd(A1rr, A1in, B1rr, B1in, m1, p1v)
                               : upd(A0rr, A0in, B0rr, B0in, m1, p1v);
            putamp<r >(s, sst, tid, n0);
            putamp<r2>(s, sst, tid, n1);
          }
        });
        if constexpr (blk_pure_pairs(BB, dreg)) __builtin_amdgcn_sched_barrier(0);
      });
    }
  } else {
    // ---- Case C: partner in another wave -> barrier-staged via xch ----
    const int ptid = tid ^ dthr;
    if constexpr (dreg < XS) {
      // partner amp within the same 4-amp chunk (dreg in {0,1,2,3})
      static_for<NAMP / XS>([&](auto kc) {
        constexpr int k = decltype(kc)::value;
        static_for<XS>([&](auto jc) {
          constexpr int j = decltype(jc)::value;
          xch[j * NTHR + tid] = getamp<XS * k + j>(s, sst, tid);
        });
        __syncthreads();
        static_for<XS>([&](auto jc) {
          constexpr int j = decltype(jc)::value;
          constexpr int r = XS * k + j;
          constexpr int p0 = cpar(r & R);
          const vf2 m = getamp<r>(s, sst, tid);
          const vf2 p = xch[(j ^ dreg) * NTHR + ptid];
          const vf2 n = p0 ? upd(A1rr, A1in, B1rr, B1in, m, p)
                            : upd(A0rr, A0in, B0rr, B0in, m, p);
          putamp<r>(s, sst, tid, n);
        });
        __syncthreads();
      });
    } else {
      // chunk-pair path (instantiated only for dreg=7):
      constexpr int kx = dreg >> 2;   // chunk XOR (>=1 here)
      constexpr int dj = dreg & 3;    // within-chunk offset
      static_for<NAMP / XS>([&](auto cc) {
        constexpr int c = decltype(cc)::value;
        if constexpr (c < (c ^ kx)) {
          constexpr int c2 = c ^ kx;
          // stage chunk c (old)
          static_for<XS>([&](auto jc) {
            constexpr int j = decltype(jc)::value;
            xch[j * NTHR + tid] = getamp<XS * c + j>(s, sst, tid);
          });
          __syncthreads();
          // compute chunk c2's new values into temps (not committed yet)
          vf2 t0, t1, t2, t3;
          {
            constexpr int r = XS * c2 + 0; constexpr int p0 = cpar(r & R);
            const vf2 m = getamp<r>(s, sst, tid);
            const vf2 p = xch[(0 ^ dj) * NTHR + ptid];
            t0 = p0 ? upd(A1rr, A1in, B1rr, B1in, m, p)
                    : upd(A0rr, A0in, B0rr, B0in, m, p);
          }
          {
            constexpr int r = XS * c2 + 1; constexpr int p0 = cpar(r & R);
            const vf2 m = getamp<r>(s, sst, tid);
            const vf2 p = xch[(1 ^ dj) * NTHR + ptid];
            t1 = p0 ? upd(A1rr, A1in, B1rr, B1in, m, p)
                    : upd(A0rr, A0in, B0rr, B0in, m, p);
          }
          {
            constexpr int r = XS * c2 + 2; constexpr int p0 = cpar(r & R);
            const vf2 m = getamp<r>(s, sst, tid);
            const vf2 p = xch[(2 ^ dj) * NTHR + ptid];
            t2 = p0 ? upd(A1rr, A1in, B1rr, B1in, m, p)
                    : upd(A0rr, A0in, B0rr, B0in, m, p);
          }
          {
            constexpr int r = XS * c2 + 3; constexpr int p0 = cpar(r & R);
            const vf2 m = getamp<r>(s, sst, tid);
            const vf2 p = xch[(3 ^ dj) * NTHR + ptid];
            t3 = p0 ? upd(A1rr, A1in, B1rr, B1in, m, p)
                    : upd(A0rr, A0in, B0rr, B0in, m, p);
          }
          __syncthreads();
          // stage chunk c2 (still-old values)
          static_for<XS>([&](auto jc) {
            constexpr int j = decltype(jc)::value;
            xch[j * NTHR + tid] = getamp<XS * c2 + j>(s, sst, tid);
          });
          __syncthreads();
          // commit chunk c from staged old c2, then commit temps to c2
          static_for<XS>([&](auto jc) {
            constexpr int j = decltype(jc)::value;
            constexpr int r = XS * c + j;
            constexpr int p0 = cpar(r & R);
            const vf2 m = getamp<r>(s, sst, tid);
            const vf2 p = xch[(j ^ dj) * NTHR + ptid];
            const vf2 n = p0 ? upd(A1rr, A1in, B1rr, B1in, m, p)
                              : upd(A0rr, A0in, B0rr, B0in, m, p);
            putamp<r>(s, sst, tid, n);
          });
          putamp<XS * c2 + 0>(s, sst, tid, t0);
          putamp<XS * c2 + 1>(s, sst, tid, t1);
          putamp<XS * c2 + 2>(s, sst, tid, t2);
          putamp<XS * c2 + 3>(s, sst, tid, t3);
          __syncthreads();
        }
      });
    }
  }
}

template<int D, int Q>
__device__ __forceinline__ void apply_all(vf2 (&s)[NREG], vf2* sst, vf2* xch,
                                          const vf2* utab, int tid) {
  apply_gate<D, Q>(s, sst, xch, utab, tid);
  __builtin_amdgcn_sched_barrier(0);   // no cross-gate scheduling overlap
  if constexpr (Q < NQ - 1) {
    apply_all<D, Q + 1>(s, sst, xch, utab, tid);
  } else if constexpr (D < NDEPTH - 1) {
    apply_all<D + 1, 0>(s, sst, xch, utab, tid);
  }
}

// 8-wave block, LDS 160 KiB -> 1 block/CU -> exactly 2 waves/SIMD.
__global__ __launch_bounds__(NTHR)
__attribute__((amdgpu_waves_per_eu(2, 2)))
void qsim_kernel(const float* __restrict__ x,
                 const float* __restrict__ params,
                 float* __restrict__ out) {
  __shared__ vf2 sst[NLDS * NTHR];             // 140 KB LDS-resident state
  __shared__ vf2 xch[XS * NTHR];               // 16 KB exchange buffer
  __shared__ vf2 utab[NDEPTH * NQ * 8];        // 4 KB pre-expanded coeffs

  const int tid = threadIdx.x;
  const int b = blockIdx.x;

  // ---- per-block gate table: U = RZ(tz) RY(ty) RX(tx), pre-expanded ----
  if (tid < NDEPTH * NQ) {
    const int d = tid / NQ, q = tid % NQ;
    const float a = tanhf(x[b * NQ + q]);
    const float tx = a + params[(d * NQ + q) * 3 + 0];
    const float ty = a + params[(d * NQ + q) * 3 + 1];
    const float tz = a + params[(d * NQ + q) * 3 + 2];
    const float cx = cosf(0.5f * tx), sx = sinf(0.5f * tx);
    const float cy = cosf(0.5f * ty), sy = sinf(0.5f * ty);
    const float cz = cosf(0.5f * tz), sz = sinf(0.5f * tz);
    // M = RY*RX entries (complex), then U = diag(ez, ezc) * M
    const float m00r = cy * cx,  m00i =  sy * sx;
    const float m01r = -sy * cx, m01i = -cy * sx;
    const float m10r = sy * cx,  m10i = -cy * sx;
    const float m11r = cy * cx,  m11i = -sy * sx;
    // ez = cz - i sz ; ezc = cz + i sz
    const float u00r = cz * m00r + sz * m00i, u00i = cz * m00i - sz * m00r;
    const float u01r = cz * m01r + sz * m01i, u01i = cz * m01i - sz * m01r;
    const float u10r = cz * m10r - sz * m10i, u10i = cz * m10i + sz * m10r;
    const float u11r = cz * m11r - sz * m11i, u11i = cz * m11i + sz * m11r;
    vf2* slot = utab + tid * 8;
    // set_0 (parity 0): A=U00, B=U01
    slot[0] = (vf2){u00r, u00r};  slot[1] = (vf2){-u00i, u00i};
    slot[2] = (vf2){u01r, u01r};  slot[3] = (vf2){-u01i, u01i};
    // set_1 (parity 1): A=U11, B=U10
    slot[4] = (vf2){u11r, u11r};  slot[5] = (vf2){-u11i, u11i};
    slot[6] = (vf2){u10r, u10r};  slot[7] = (vf2){-u10i, u10i};
  }

  // ---- state init: |0..0> (amp x=0 lives at tid 0, r 0) ----
  vf2 s[NREG];
  static_for<NREG>([&](auto rc) { s[decltype(rc)::value] = (vf2){0.f, 0.f}; });
  static_for<NLDS>([&](auto ic) {
    sst[decltype(ic)::value * NTHR + tid] = (vf2){0.f, 0.f};
  });
  if (tid == 0) s[0].x = 1.0f;
  __syncthreads();

  // ---- all 64 rotation gates (CNOTs folded into constexpr masks) ----
  apply_all<0, 0>(s, sst, xch, utab, tid);

  // ---- Z expectations, two passes of 8 to cap register pressure ----
  __syncthreads();                 // xch free for reuse as reduction buffer
  float* red = (float*)xch;
  static_for<2>([&](auto hc) {
    constexpr int H = decltype(hc)::value;
    float z[8];
    static_for<8>([&](auto qc) { z[decltype(qc)::value] = 0.f; });
    static_for<NAMP>([&](auto rc) {
      constexpr int r = decltype(rc)::value;
      const vf2 v = getamp<r>(s, sst, tid);
      const float pr = v.x * v.x + v.y * v.y;
      static_for<8>([&](auto qc) {
        constexpr int qq = decltype(qc)::value;
        constexpr int q = 8 * H + qq;
        constexpr bool neg = cpar(r & MK.meas[q]) != 0;
        z[qq] = neg ? (z[qq] - pr) : (z[qq] + pr);
      });
    });
    static_for<8>([&](auto qc) {
      constexpr int qq = decltype(qc)::value;
      constexpr int q = 8 * H + qq;
      const int ptq = __popc(tid & (MK.meas[q] >> 7)) & 1;
      float v = ptq ? -z[qq] : z[qq];
      static_for<6>([&](auto ic) {
        constexpr int sh = 32 >> decltype(ic)::value;
        v += __shfl_xor(v, sh);
      });
      z[qq] = v;
    });
    if ((tid & 63) == 0) {
      const int w = tid >> 6;      // 8 waves
      static_for<8>([&](auto qc) {
        constexpr int qq = decltype(qc)::value;
        red[w * 8 + qq] = z[qq];
      });
    }
    __syncthreads();
    if (tid < 8) {
      float acc = 0.f;
#pragma unroll
      for (int w = 0; w < 8; ++w) acc += red[w * 8 + tid];
      out[b * NQ + 8 * H + tid] = acc;
    }
    __syncthreads();
  });
}

extern "C" void kernel_launch(void* const* d_in, const int* in_sizes, int n_in,
                              void* d_out, int out_size, void* d_ws, size_t ws_size,
                              hipStream_t stream) {
  const float* x      = (const float*)d_in[0];
  const float* params = (const float*)d_in[1];
  float* out          = (float*)d_out;
  qsim_kernel<<<dim3(NBATCH), dim3(NTHR), 0, stream>>>(x, params, out);
}

// Round 9
// 854.348 us; speedup vs baseline: 18.3274x; 1.0017x over previous
//
#include <hip/hip_runtime.h>
#include <cstdint>
#include <utility>

#define NQ 16
#define NDEPTH 4
#define NBATCH 512
#define NTHR 512      // threads per block (8 waves = 2 waves/SIMD, pinned)
#define NAMP 128      // amps per thread (65536 / NTHR)
#define NREG 93       // amps in registers (186 VGPRs)
#define NLDS (NAMP - NREG)   // 35 amps in LDS: 35*512*8 = 140 KB

typedef float vf2 __attribute__((ext_vector_type(2)));
typedef float vf4 __attribute__((ext_vector_type(4)));

// ---------------------------------------------------------------------------
// Compile-time GF(2) tracking of the CNOT ring (verified r1/r4/r6/r7/r8,
// passes at absmax 6.1e-5).  Physical index x (16 bits): bit b <-> wire 15-b.
// Rotation on logical wire q at layer d:
//   pair mask  Delta = A^{-1} e_p, parity row R = row_p(A), p = 15-q.
// Layout: x = (tid << 7) | r ; reg = x[6:0], lane = tid[5:0], wave = tid[8:6].
// Census: A=22 gates (dthr==0), B=24 (lane only), C=18 (wave-crossing,
// dreg in {0,1,2,3,7}).
// ---------------------------------------------------------------------------
struct Masks {
  unsigned short delta[NDEPTH][NQ];
  unsigned short rowm[NDEPTH][NQ];
  unsigned short meas[NQ];
};

constexpr Masks make_masks() {
  Masks m = {};
  unsigned short Arow[NQ] = {};
  unsigned short Ainv[NQ] = {};
  for (int p = 0; p < NQ; ++p) {
    Arow[p] = (unsigned short)(1u << p);
    Ainv[p] = (unsigned short)(1u << p);
  }
  for (int d = 0; d < NDEPTH; ++d) {
    for (int q = 0; q < NQ; ++q) {
      m.delta[d][q] = Ainv[15 - q];
      m.rowm[d][q]  = Arow[15 - q];
    }
    for (int q = 0; q < NQ - 1; ++q) {    // CNOT(q, q+1)
      const int pc = 15 - q, pt = 15 - (q + 1);
      Arow[pt] = (unsigned short)(Arow[pt] ^ Arow[pc]);
      Ainv[pc] = (unsigned short)(Ainv[pc] ^ Ainv[pt]);
    }
    {                                      // CNOT(15, 0)
      const int pc = 0, pt = 15;
      Arow[pt] = (unsigned short)(Arow[pt] ^ Arow[pc]);
      Ainv[pc] = (unsigned short)(Ainv[pc] ^ Ainv[pt]);
    }
  }
  for (int q = 0; q < NQ; ++q) m.meas[q] = Arow[15 - q];
  return m;
}

constexpr Masks MK = make_masks();

constexpr int cpar(int v) {
  int p = 0;
  for (int i = 0; i < 16; ++i) p ^= (v >> i) & 1;
  return p;
}

template<typename F, int... Is>
__device__ __forceinline__ void sf_impl(F&& f, std::integer_sequence<int, Is...>) {
  (f(std::integral_constant<int, Is>{}), ...);
}
template<int N, typename F>
__device__ __forceinline__ void static_for(F&& f) {
  sf_impl(f, std::make_integer_sequence<int, N>{});
}

__device__ __forceinline__ vf2 swap2(vf2 v) {
  return __builtin_shufflevector(v, v, 1, 0);
}
// new = A*m + B*p (complex), coeffs pre-expanded: Arr=(A.re,A.re),
// Ain=(-A.im,A.im), etc.  4 packed ops (v_pk_mul/fma_f32).
__device__ __forceinline__ vf2 upd(vf2 Arr, vf2 Ain, vf2 Brr, vf2 Bin,
                                   vf2 m, vf2 p) {
  vf2 t = Arr * m;
  t = __builtin_elementwise_fma(Ain, swap2(m), t);
  t = __builtin_elementwise_fma(Brr, p, t);
  t = __builtin_elementwise_fma(Bin, swap2(p), t);
  return t;
}

// ---- compile-time-dispatched state accessors: reg for r<NREG, LDS above ----
template<int r>
__device__ __forceinline__ vf2 getamp(const vf2 (&s)[NREG], const vf2* sst, int tid) {
  if constexpr (r < NREG) return s[r];
  else return sst[(r - NREG) * NTHR + tid];
}
template<int r>
__device__ __forceinline__ void putamp(vf2 (&s)[NREG], vf2* sst, int tid, vf2 v) {
  if constexpr (r < NREG) s[r] = v;
  else sst[(r - NREG) * NTHR + tid] = v;
}

// ---------------------------------------------------------------------------
// One rotation gate.  Element of total parity b (= constexpr reg-parity ^
// runtime thread-parity pt): new = U[b][b]*mine + U[b][1-b]*partner.
// Coefficients pre-expanded in LDS as float4 pairs; the set for each parity
// is chosen by pt via the LDS address (b128 loads, no selects).
// ---------------------------------------------------------------------------
template<int D, int Q>
__device__ __forceinline__ void apply_gate(vf2 (&s)[NREG], vf2* sst, vf4* xch,
                                           const vf4* utab, int tid) {
  constexpr int DLT   = MK.delta[D][Q];
  constexpr int R     = MK.rowm[D][Q];
  constexpr int dreg  = DLT & (NAMP - 1);
  constexpr int dthr  = DLT >> 7;
  constexpr int dlane = dthr & 63;
  constexpr int dwave = dthr >> 6;

  const int pt = __popc(tid & (R >> 7)) & 1;
  const int gbase = (D * NQ + Q) * 4;
  const int o0 = pt << 1;                 // float4 offset of set for reg-parity 0
  const int o1 = 2 - o0;                  // set for reg-parity 1
  const vf4 ca0 = utab[gbase + o0], cb0 = utab[gbase + o0 + 1];
  const vf4 ca1 = utab[gbase + o1], cb1 = utab[gbase + o1 + 1];
  const vf2 A0rr = {ca0.x, ca0.y}, A0in = {ca0.z, ca0.w};
  const vf2 B0rr = {cb0.x, cb0.y}, B0in = {cb0.z, cb0.w};
  const vf2 A1rr = {ca1.x, ca1.y}, A1in = {ca1.z, ca1.w};
  const vf2 B1rr = {cb1.x, cb1.y}, B1in = {cb1.z, cb1.w};

  if constexpr (dthr == 0) {
    // ---- Case A: pair entirely within this thread (no fences: reg-local) ----
    static_for<NAMP>([&](auto rc) {
      constexpr int r = decltype(rc)::value;
      constexpr int r2 = r ^ dreg;
      if constexpr (r < r2) {
        constexpr int p0 = cpar(r & R);
        constexpr int p1 = cpar(r2 & R);     // explicit (r3 lesson)
        const vf2 a = getamp<r >(s, sst, tid);
        const vf2 c = getamp<r2>(s, sst, tid);
        const vf2 n0 = p0 ? upd(A1rr, A1in, B1rr, B1in, a, c)
                           : upd(A0rr, A0in, B0rr, B0in, a, c);
        const vf2 n1 = p1 ? upd(A1rr, A1in, B1rr, B1in, c, a)
                           : upd(A0rr, A0in, B0rr, B0in, c, a);
        putamp<r >(s, sst, tid, n0);
        putamp<r2>(s, sst, tid, n1);
      }
    });
  } else if constexpr (dwave == 0) {
    // ---- Case B: partner in same wave -> shuffles; fence per 32 amps ----
    if constexpr (dreg == 0) {
      static_for<4>([&](auto bc) {
        constexpr int BB = decltype(bc)::value;
        static_for<32>([&](auto jc) {
          constexpr int r = 32 * BB + decltype(jc)::value;
          constexpr int p0 = cpar(r & R);
          const vf2 m = getamp<r>(s, sst, tid);
          vf2 p;
          p.x = __shfl_xor(m.x, dlane);
          p.y = __shfl_xor(m.y, dlane);
          const vf2 n = p0 ? upd(A1rr, A1in, B1rr, B1in, m, p)
                            : upd(A0rr, A0in, B0rr, B0in, m, p);
          putamp<r>(s, sst, tid, n);
        });
        __builtin_amdgcn_sched_barrier(0);
      });
    } else {
      static_for<4>([&](auto bc) {
        constexpr int BB = decltype(bc)::value;
        static_for<32>([&](auto jc) {
          constexpr int r = 32 * BB + decltype(jc)::value;
          constexpr int r2 = r ^ dreg;
          if constexpr (r < r2) {
            constexpr int p0 = cpar(r & R);
            constexpr int p1 = cpar(r2 & R);
            const vf2 m0 = getamp<r >(s, sst, tid);
            const vf2 m1 = getamp<r2>(s, sst, tid);
            vf2 p0v, p1v;
            p0v.x = __shfl_xor(m1.x, dlane);  // partner's amp r^dreg
            p0v.y = __shfl_xor(m1.y, dlane);
            p1v.x = __shfl_xor(m0.x, dlane);  // partner's amp r
            p1v.y = __shfl_xor(m0.y, dlane);
            const vf2 n0 = p0 ? upd(A1rr, A1in, B1rr, B1in, m0, p0v)
                               : upd(A0rr, A0in, B0rr, B0in, m0, p0v);
            const vf2 n1 = p1 ? upd(A1rr, A1in, B1rr, B1in, m1, p1v)
                               : upd(A0rr, A0in, B0rr, B0in, m1, p1v);
            putamp<r >(s, sst, tid, n0);
            putamp<r2>(s, sst, tid, n1);
          }
        });
        __builtin_amdgcn_sched_barrier(0);
      });
    }
  } else {
    // ---- Case C: partner in another wave -> barrier-staged via b128 xch ----
    const int ptid = tid ^ dthr;
    if constexpr (dreg < 4) {
      // partner amp within the same 4-amp chunk (dreg in {0,1,2,3})
      static_for<NAMP / 4>([&](auto kc) {
        constexpr int k = decltype(kc)::value;
        const vf2 m0 = getamp<4 * k + 0>(s, sst, tid);
        const vf2 m1 = getamp<4 * k + 1>(s, sst, tid);
        const vf2 m2 = getamp<4 * k + 2>(s, sst, tid);
        const vf2 m3 = getamp<4 * k + 3>(s, sst, tid);
        xch[tid]        = (vf4){m0.x, m0.y, m1.x, m1.y};
        xch[NTHR + tid] = (vf4){m2.x, m2.y, m3.x, m3.y};
        __syncthreads();
        const vf4 q0 = xch[ptid];
        const vf4 q1 = xch[NTHR + ptid];
        // partner amps: 0=q0.xy 1=q0.zw 2=q1.xy 3=q1.zw (selection constexpr)
        static_for<4>([&](auto jc) {
          constexpr int j = decltype(jc)::value;
          constexpr int r = 4 * k + j;
          constexpr int jp = j ^ dreg;
          constexpr int p0 = cpar(r & R);
          const vf2 m = (j == 0) ? m0 : (j == 1) ? m1 : (j == 2) ? m2 : m3;
          vf2 p;
          if constexpr (jp == 0)      p = (vf2){q0.x, q0.y};
          else if constexpr (jp == 1) p = (vf2){q0.z, q0.w};
          else if constexpr (jp == 2) p = (vf2){q1.x, q1.y};
          else                        p = (vf2){q1.z, q1.w};
          const vf2 n = p0 ? upd(A1rr, A1in, B1rr, B1in, m, p)
                            : upd(A0rr, A0in, B0rr, B0in, m, p);
          putamp<r>(s, sst, tid, n);
        });
        __syncthreads();
      });
    } else {
      // chunk-pair path (dreg >= 4; instantiated only for dreg=7):
      // chunk c pairs with c2=c^kx; partner of (c,j) is (c2, j^dj) at ptid.
      constexpr int kx = dreg >> 2;
      constexpr int dj = dreg & 3;
      static_for<NAMP / 4>([&](auto cc) {
        constexpr int c = decltype(cc)::value;
        if constexpr (c < (c ^ kx)) {
          constexpr int c2 = c ^ kx;
          // stage chunk c (old)
          {
            const vf2 a0 = getamp<4 * c + 0>(s, sst, tid);
            const vf2 a1 = getamp<4 * c + 1>(s, sst, tid);
            const vf2 a2 = getamp<4 * c + 2>(s, sst, tid);
            const vf2 a3 = getamp<4 * c + 3>(s, sst, tid);
            xch[tid]        = (vf4){a0.x, a0.y, a1.x, a1.y};
            xch[NTHR + tid] = (vf4){a2.x, a2.y, a3.x, a3.y};
          }
          __syncthreads();
          // compute chunk c2's new values into temps (not committed yet)
          vf2 t0, t1, t2, t3;
          {
            const vf4 q0 = xch[ptid];
            const vf4 q1 = xch[NTHR + ptid];
            static_for<4>([&](auto jc) {
              constexpr int j = decltype(jc)::value;
              constexpr int r = 4 * c2 + j;
              constexpr int jp = j ^ dj;     // partner slot within chunk c
              constexpr int p0 = cpar(r & R);
              const vf2 m = getamp<r>(s, sst, tid);
              vf2 p;
              if constexpr (jp == 0)      p = (vf2){q0.x, q0.y};
              else if constexpr (jp == 1) p = (vf2){q0.z, q0.w};
              else if constexpr (jp == 2) p = (vf2){q1.x, q1.y};
              else                        p = (vf2){q1.z, q1.w};
              const vf2 n = p0 ? upd(A1rr, A1in, B1rr, B1in, m, p)
                                : upd(A0rr, A0in, B0rr, B0in, m, p);
              if constexpr (j == 0) t0 = n;
              else if constexpr (j == 1) t1 = n;
              else if constexpr (j == 2) t2 = n;
              else t3 = n;
            });
          }
          __syncthreads();
          // stage chunk c2 (still-old values; temps not committed)
          {
            const vf2 a0 = getamp<4 * c2 + 0>(s, sst, tid);
            const vf2 a1 = getamp<4 * c2 + 1>(s, sst, tid);
            const vf2 a2 = getamp<4 * c2 + 2>(s, sst, tid);
            const vf2 a3 = getamp<4 * c2 + 3>(s, sst, tid);
            xch[tid]        = (vf4){a0.x, a0.y, a1.x, a1.y};
            xch[NTHR + tid] = (vf4){a2.x, a2.y, a3.x, a3.y};
          }
          __syncthreads();
          // commit chunk c from staged old c2, then commit temps to c2
          {
            const vf4 q0 = xch[ptid];
            const vf4 q1 = xch[NTHR + ptid];
            static_for<4>([&](auto jc) {
              constexpr int j = decltype(jc)::value;
              constexpr int r = 4 * c + j;
              constexpr int jp = j ^ dj;     // partner slot within chunk c2
              constexpr int p0 = cpar(r & R);
              const vf2 m = getamp<r>(s, sst, tid);
              vf2 p;
              if constexpr (jp == 0)      p = (vf2){q0.x, q0.y};
              else if constexpr (jp == 1) p = (vf2){q0.z, q0.w};
              else if constexpr (jp == 2) p = (vf2){q1.x, q1.y};
              else                        p = (vf2){q1.z, q1.w};
              const vf2 n = p0 ? upd(A1rr, A1in, B1rr, B1in, m, p)
                                : upd(A0rr, A0in, B0rr, B0in, m, p);
              putamp<r>(s, sst, tid, n);
            });
          }
          putamp<4 * c2 + 0>(s, sst, tid, t0);
          putamp<4 * c2 + 1>(s, sst, tid, t1);
          putamp<4 * c2 + 2>(s, sst, tid, t2);
          putamp<4 * c2 + 3>(s, sst, tid, t3);
          __syncthreads();
        }
      });
    }
  }
}

template<int D, int Q>
__device__ __forceinline__ void apply_all(vf2 (&s)[NREG], vf2* sst, vf4* xch,
                                          const vf4* utab, int tid) {
  apply_gate<D, Q>(s, sst, xch, utab, tid);
  __builtin_amdgcn_sched_barrier(0);   // no cross-gate scheduling overlap
  if constexpr (Q < NQ - 1) {
    apply_all<D, Q + 1>(s, sst, xch, utab, tid);
  } else if constexpr (D < NDEPTH - 1) {
    apply_all<D + 1, 0>(s, sst, xch, utab, tid);
  }
}

// 8-wave block, LDS 160 KiB -> 1 block/CU -> exactly 2 waves/SIMD.
__global__ __launch_bounds__(NTHR)
__attribute__((amdgpu_waves_per_eu(2, 2)))
void qsim_kernel(const float* __restrict__ x,
                 const float* __restrict__ params,
                 float* __restrict__ out) {
  __shared__ vf2 sst[NLDS * NTHR];             // 140 KB LDS-resident state
  __shared__ vf4 xch[2 * NTHR];                // 16 KB exchange buffer (b128)
  __shared__ vf4 utab[NDEPTH * NQ * 4];        // 4 KB pre-expanded coeffs

  const int tid = threadIdx.x;
  const int b = blockIdx.x;

  // ---- per-block gate table: U = RZ(tz) RY(ty) RX(tx), pre-expanded ----
  if (tid < NDEPTH * NQ) {
    const int d = tid / NQ, q = tid % NQ;
    const float a = tanhf(x[b * NQ + q]);
    const float tx = a + params[(d * NQ + q) * 3 + 0];
    const float ty = a + params[(d * NQ + q) * 3 + 1];
    const float tz = a + params[(d * NQ + q) * 3 + 2];
    const float cx = cosf(0.5f * tx), sx = sinf(0.5f * tx);
    const float cy = cosf(0.5f * ty), sy = sinf(0.5f * ty);
    const float cz = cosf(0.5f * tz), sz = sinf(0.5f * tz);
    // M = RY*RX entries (complex), then U = diag(ez, ezc) * M
    const float m00r = cy * cx,  m00i =  sy * sx;
    const float m01r = -sy * cx, m01i = -cy * sx;
    const float m10r = sy * cx,  m10i = -cy * sx;
    const float m11r = cy * cx,  m11i = -sy * sx;
    // ez = cz - i sz ; ezc = cz + i sz
    const float u00r = cz * m00r + sz * m00i, u00i = cz * m00i - sz * m00r;
    const float u01r = cz * m01r + sz * m01i, u01i = cz * m01i - sz * m01r;
    const float u10r = cz * m10r - sz * m10i, u10i = cz * m10i + sz * m10r;
    const float u11r = cz * m11r - sz * m11i, u11i = cz * m11i + sz * m11r;
    vf4* slot = utab + tid * 4;
    // set_0 (parity 0): A=U00, B=U01 ; set_1 (parity 1): A=U11, B=U10
    slot[0] = (vf4){u00r, u00r, -u00i, u00i};
    slot[1] = (vf4){u01r, u01r, -u01i, u01i};
    slot[2] = (vf4){u11r, u11r, -u11i, u11i};
    slot[3] = (vf4){u10r, u10r, -u10i, u10i};
  }

  // ---- state init: |0..0> (amp x=0 lives at tid 0, r 0) ----
  vf2 s[NREG];
  static_for<NREG>([&](auto rc) { s[decltype(rc)::value] = (vf2){0.f, 0.f}; });
  static_for<NLDS>([&](auto ic) {
    sst[decltype(ic)::value * NTHR + tid] = (vf2){0.f, 0.f};
  });
  if (tid == 0) s[0].x = 1.0f;
  __syncthreads();

  // ---- all 64 rotation gates (CNOTs folded into constexpr masks) ----
  apply_all<0, 0>(s, sst, xch, utab, tid);

  // ---- Z expectations, two passes of 8 to cap register pressure ----
  __syncthreads();                 // xch free for reuse as reduction buffer
  float* red = (float*)xch;
  static_for<2>([&](auto hc) {
    constexpr int H = decltype(hc)::value;
    float z[8];
    static_for<8>([&](auto qc) { z[decltype(qc)::value] = 0.f; });
    static_for<NAMP>([&](auto rc) {
      constexpr int r = decltype(rc)::value;
      const vf2 v = getamp<r>(s, sst, tid);
      const float pr = v.x * v.x + v.y * v.y;
      static_for<8>([&](auto qc) {
        constexpr int qq = decltype(qc)::value;
        constexpr int q = 8 * H + qq;
        constexpr bool neg = cpar(r & MK.meas[q]) != 0;
        z[qq] = neg ? (z[qq] - pr) : (z[qq] + pr);
      });
    });
    static_for<8>([&](auto qc) {
      constexpr int qq = decltype(qc)::value;
      constexpr int q = 8 * H + qq;
      const int ptq = __popc(tid & (MK.meas[q] >> 7)) & 1;
      float v = ptq ? -z[qq] : z[qq];
      static_for<6>([&](auto ic) {
        constexpr int sh = 32 >> decltype(ic)::value;
        v += __shfl_xor(v, sh);
      });
      z[qq] = v;
    });
    if ((tid & 63) == 0) {
      const int w = tid >> 6;      // 8 waves
      static_for<8>([&](auto qc) {
        constexpr int qq = decltype(qc)::value;
        red[w * 8 + qq] = z[qq];
      });
    }
    __syncthreads();
    if (tid < 8) {
      float acc = 0.f;
#pragma unroll
      for (int w = 0; w < 8; ++w) acc += red[w * 8 + tid];
      out[b * NQ + 8 * H + tid] = acc;
    }
    __syncthreads();
  });
}

extern "C" void kernel_launch(void* const* d_in, const int* in_sizes, int n_in,
                              void* d_out, int out_size, void* d_ws, size_t ws_size,
                              hipStream_t stream) {
  const float* x      = (const float*)d_in[0];
  const float* params = (const float*)d_in[1];
  float* out          = (float*)d_out;
  qsim_kernel<<<dim3(NBATCH), dim3(NTHR), 0, stream>>>(x, params, out);
}

// Round 11
// 769.846 us; speedup vs baseline: 20.3391x; 1.1098x over previous
//
#include <hip/hip_runtime.h>
#include <cstdint>
#include <utility>

#define NQ 16
#define NDEPTH 4
#define NBATCH 512
#define NTHR 512      // threads per block (8 waves = 2 waves/SIMD, pinned)
#define NAMP 128      // amps per thread (65536 / NTHR)
#define NREG 97       // amps in registers (194 VGPRs)
#define NLDS (NAMP - NREG)   // 31 amps in LDS: 31*512*8 = 124 KB

typedef float vf2 __attribute__((ext_vector_type(2)));
typedef float vf4 __attribute__((ext_vector_type(4)));

// ---------------------------------------------------------------------------
// Compile-time GF(2) tracking of the CNOT ring (verified r1/r4/r6-r9,
// passes at absmax 6.1e-5).  Physical index x (16 bits): bit b <-> wire 15-b.
// Rotation on logical wire q at layer d:
//   pair mask  Delta = A^{-1} e_p, parity row R = row_p(A), p = 15-q.
// Layout: x = (tid << 7) | r ; reg = x[6:0], lane = tid[5:0], wave = tid[8:6].
// C-gate (wave-crossing) dregs: {0,1,2,3,7}.  B-gate dlanes include
// DPP-expressible XORs {1,2,3,7,15} (10 of 24 gates).
// ---------------------------------------------------------------------------
struct Masks {
  unsigned short delta[NDEPTH][NQ];
  unsigned short rowm[NDEPTH][NQ];
  unsigned short meas[NQ];
};

constexpr Masks make_masks() {
  Masks m = {};
  unsigned short Arow[NQ] = {};
  unsigned short Ainv[NQ] = {};
  for (int p = 0; p < NQ; ++p) {
    Arow[p] = (unsigned short)(1u << p);
    Ainv[p] = (unsigned short)(1u << p);
  }
  for (int d = 0; d < NDEPTH; ++d) {
    for (int q = 0; q < NQ; ++q) {
      m.delta[d][q] = Ainv[15 - q];
      m.rowm[d][q]  = Arow[15 - q];
    }
    for (int q = 0; q < NQ - 1; ++q) {    // CNOT(q, q+1)
      const int pc = 15 - q, pt = 15 - (q + 1);
      Arow[pt] = (unsigned short)(Arow[pt] ^ Arow[pc]);
      Ainv[pc] = (unsigned short)(Ainv[pc] ^ Ainv[pt]);
    }
    {                                      // CNOT(15, 0)
      const int pc = 0, pt = 15;
      Arow[pt] = (unsigned short)(Arow[pt] ^ Arow[pc]);
      Ainv[pc] = (unsigned short)(Ainv[pc] ^ Ainv[pt]);
    }
  }
  for (int q = 0; q < NQ; ++q) m.meas[q] = Arow[15 - q];
  return m;
}

constexpr Masks MK = make_masks();

constexpr int cpar(int v) {
  int p = 0;
  for (int i = 0; i < 16; ++i) p ^= (v >> i) & 1;
  return p;
}

// DPP ctrl encoding for lane-XOR patterns expressible in one v_mov_dpp:
//  xor1 = quad_perm[1,0,3,2] = 0xB1 ; xor2 = [2,3,0,1] = 0x4E ;
//  xor3 = [3,2,1,0] = 0x1B ; xor7 = ROW_HALF_MIRROR 0x141 ;
//  xor15 = ROW_MIRROR 0x140.  Others: -1 (fall back to shuffle).
constexpr int dppctrl(int dl) {
  return dl == 1 ? 0xB1 : dl == 2 ? 0x4E : dl == 3 ? 0x1B
       : dl == 7 ? 0x141 : dl == 15 ? 0x140 : -1;
}

template<typename F, int... Is>
__device__ __forceinline__ void sf_impl(F&& f, std::integer_sequence<int, Is...>) {
  (f(std::integral_constant<int, Is>{}), ...);
}
template<int N, typename F>
__device__ __forceinline__ void static_for(F&& f) {
  sf_impl(f, std::make_integer_sequence<int, N>{});
}

__device__ __forceinline__ vf2 swap2(vf2 v) {
  return __builtin_shufflevector(v, v, 1, 0);
}
// new = A*m + B*p (complex), coeffs pre-expanded: Arr=(A.re,A.re),
// Ain=(-A.im,A.im), etc.  4 packed ops (v_pk_mul/fma_f32).
__device__ __forceinline__ vf2 upd(vf2 Arr, vf2 Ain, vf2 Brr, vf2 Bin,
                                   vf2 m, vf2 p) {
  vf2 t = Arr * m;
  t = __builtin_elementwise_fma(Ain, swap2(m), t);
  t = __builtin_elementwise_fma(Brr, p, t);
  t = __builtin_elementwise_fma(Bin, swap2(p), t);
  return t;
}

// lane-XOR exchange: DPP (VALU pipe, no DS op) when expressible, else shuffle
template<int DL>
__device__ __forceinline__ vf2 xlane(vf2 v) {
  constexpr int C = dppctrl(DL);
  if constexpr (C >= 0) {
    int xi = __float_as_int(v.x), yi = __float_as_int(v.y);
    xi = __builtin_amdgcn_update_dpp(xi, xi, C, 0xF, 0xF, true);
    yi = __builtin_amdgcn_update_dpp(yi, yi, C, 0xF, 0xF, true);
    return (vf2){__int_as_float(xi), __int_as_float(yi)};
  } else {
    vf2 p;
    p.x = __shfl_xor(v.x, DL);
    p.y = __shfl_xor(v.y, DL);
    return p;
  }
}

// ---- compile-time-dispatched state accessors: reg for r<NREG, LDS above ----
template<int r>
__device__ __forceinline__ vf2 getamp(const vf2 (&s)[NREG], const vf2* sst, int tid) {
  if constexpr (r < NREG) return s[r];
  else return sst[(r - NREG) * NTHR + tid];
}
template<int r>
__device__ __forceinline__ void putamp(vf2 (&s)[NREG], vf2* sst, int tid, vf2 v) {
  if constexpr (r < NREG) s[r] = v;
  else sst[(r - NREG) * NTHR + tid] = v;
}
template<int r>
__device__ __forceinline__ vf4 pack2(const vf2 (&s)[NREG], const vf2* sst, int tid) {
  const vf2 a = getamp<r    >(s, sst, tid);
  const vf2 b = getamp<r + 1>(s, sst, tid);
  return (vf4){a.x, a.y, b.x, b.y};
}

// ---------------------------------------------------------------------------
// One rotation gate.  Element of total parity b (= constexpr reg-parity ^
// runtime thread-parity pt): new = U[b][b]*mine + U[b][1-b]*partner.
// Coefficients pre-expanded in LDS as float4 pairs; the set for each parity
// is chosen by pt via the LDS address (b128 loads, no selects).
// ---------------------------------------------------------------------------
template<int D, int Q>
__device__ __forceinline__ void apply_gate(vf2 (&s)[NREG], vf2* sst, vf4* xch,
                                           const vf4* utab, int tid) {
  constexpr int DLT   = MK.delta[D][Q];
  constexpr int R     = MK.rowm[D][Q];
  constexpr int dreg  = DLT & (NAMP - 1);
  constexpr int dthr  = DLT >> 7;
  constexpr int dlane = dthr & 63;
  constexpr int dwave = dthr >> 6;

  const int pt = __popc(tid & (R >> 7)) & 1;
  const int gbase = (D * NQ + Q) * 4;
  const int o0 = pt << 1;                 // float4 offset of set for reg-parity 0
  const int o1 = 2 - o0;                  // set for reg-parity 1
  const vf4 ca0 = utab[gbase + o0], cb0 = utab[gbase + o0 + 1];
  const vf4 ca1 = utab[gbase + o1], cb1 = utab[gbase + o1 + 1];
  const vf2 A0rr = {ca0.x, ca0.y}, A0in = {ca0.z, ca0.w};
  const vf2 B0rr = {cb0.x, cb0.y}, B0in = {cb0.z, cb0.w};
  const vf2 A1rr = {ca1.x, ca1.y}, A1in = {ca1.z, ca1.w};
  const vf2 B1rr = {cb1.x, cb1.y}, B1in = {cb1.z, cb1.w};

  if constexpr (dthr == 0) {
    // ---- Case A: pair entirely within this thread ----
    static_for<NAMP>([&](auto rc) {
      constexpr int r = decltype(rc)::value;
      constexpr int r2 = r ^ dreg;
      if constexpr (r < r2) {
        constexpr int p0 = cpar(r & R);
        constexpr int p1 = cpar(r2 & R);     // explicit (r3 lesson)
        const vf2 a = getamp<r >(s, sst, tid);
        const vf2 c = getamp<r2>(s, sst, tid);
        const vf2 n0 = p0 ? upd(A1rr, A1in, B1rr, B1in, a, c)
                           : upd(A0rr, A0in, B0rr, B0in, a, c);
        const vf2 n1 = p1 ? upd(A1rr, A1in, B1rr, B1in, c, a)
                           : upd(A0rr, A0in, B0rr, B0in, c, a);
        putamp<r >(s, sst, tid, n0);
        putamp<r2>(s, sst, tid, n1);
      }
    });
  } else if constexpr (dwave == 0) {
    // ---- Case B: partner in same wave -> DPP/shuffle; fence per 32 amps ----
    if constexpr (dreg == 0) {
      static_for<4>([&](auto bc) {
        constexpr int BB = decltype(bc)::value;
        static_for<32>([&](auto jc) {
          constexpr int r = 32 * BB + decltype(jc)::value;
          constexpr int p0 = cpar(r & R);
          const vf2 m = getamp<r>(s, sst, tid);
          const vf2 p = xlane<dlane>(m);
          const vf2 n = p0 ? upd(A1rr, A1in, B1rr, B1in, m, p)
                            : upd(A0rr, A0in, B0rr, B0in, m, p);
          putamp<r>(s, sst, tid, n);
        });
        __builtin_amdgcn_sched_barrier(0);
      });
    } else {
      static_for<4>([&](auto bc) {
        constexpr int BB = decltype(bc)::value;
        static_for<32>([&](auto jc) {
          constexpr int r = 32 * BB + decltype(jc)::value;
          constexpr int r2 = r ^ dreg;
          if constexpr (r < r2) {
            constexpr int p0 = cpar(r & R);
            constexpr int p1 = cpar(r2 & R);
            const vf2 m0 = getamp<r >(s, sst, tid);
            const vf2 m1 = getamp<r2>(s, sst, tid);
            const vf2 p0v = xlane<dlane>(m1);   // partner's amp r^dreg
            const vf2 p1v = xlane<dlane>(m0);   // partner's amp r
            const vf2 n0 = p0 ? upd(A1rr, A1in, B1rr, B1in, m0, p0v)
                               : upd(A0rr, A0in, B0rr, B0in, m0, p0v);
            const vf2 n1 = p1 ? upd(A1rr, A1in, B1rr, B1in, m1, p1v)
                               : upd(A0rr, A0in, B0rr, B0in, m1, p1v);
            putamp<r >(s, sst, tid, n0);
            putamp<r2>(s, sst, tid, n1);
          }
        });
        __builtin_amdgcn_sched_barrier(0);
      });
    }
  } else {
    // ---- Case C: partner in another wave -> barrier-staged b128 exchange ----
    // 8 amps per round (chunks c, c^kc through 4 b128 slots), 2 barriers,
    // 16 rounds per gate (32 barriers vs 64 in the 4-amp scheme).
    constexpr int kc0 = dreg >> 2;
    constexpr int kc  = kc0 ? kc0 : 1;
    const int ptid = tid ^ dthr;
    static_for<NAMP / 4>([&](auto cc) {
      constexpr int c = decltype(cc)::value;
      if constexpr (c < (c ^ kc)) {
        constexpr int c2 = c ^ kc;
        // stage own 8 amps: slots 0,1 = chunk c ; slots 2,3 = chunk c2
        xch[0 * NTHR + tid] = pack2<4 * c  + 0>(s, sst, tid);
        xch[1 * NTHR + tid] = pack2<4 * c  + 2>(s, sst, tid);
        xch[2 * NTHR + tid] = pack2<4 * c2 + 0>(s, sst, tid);
        xch[3 * NTHR + tid] = pack2<4 * c2 + 2>(s, sst, tid);
        __syncthreads();
        const vf4 q0 = xch[0 * NTHR + ptid];
        const vf4 q1 = xch[1 * NTHR + ptid];
        const vf4 q2 = xch[2 * NTHR + ptid];
        const vf4 q3 = xch[3 * NTHR + ptid];
        static_for<8>([&](auto jc) {
          constexpr int jj = decltype(jc)::value;
          constexpr int r  = (jj < 4) ? (4 * c + jj) : (4 * c2 + (jj - 4));
          constexpr int rp = r ^ dreg;            // partner amp index
          constexpr int sb = ((rp >> 2) == c) ? 0 : 2;
          constexpr int slot = sb + ((rp & 3) >> 1);
          constexpr int half = rp & 1;
          constexpr int p0 = cpar(r & R);
          vf2 p;
          if constexpr (slot == 0)      p = half ? (vf2){q0.z, q0.w} : (vf2){q0.x, q0.y};
          else if constexpr (slot == 1) p = half ? (vf2){q1.z, q1.w} : (vf2){q1.x, q1.y};
          else if constexpr (slot == 2) p = half ? (vf2){q2.z, q2.w} : (vf2){q2.x, q2.y};
          else                          p = half ? (vf2){q3.z, q3.w} : (vf2){q3.x, q3.y};
          const vf2 m = getamp<r>(s, sst, tid);
          const vf2 n = p0 ? upd(A1rr, A1in, B1rr, B1in, m, p)
                            : upd(A0rr, A0in, B0rr, B0in, m, p);
          putamp<r>(s, sst, tid, n);
        });
        __syncthreads();
      }
    });
  }
}

template<int D, int Q>
__device__ __forceinline__ void apply_all(vf2 (&s)[NREG], vf2* sst, vf4* xch,
                                          const vf4* utab, int tid) {
  apply_gate<D, Q>(s, sst, xch, utab, tid);
  __builtin_amdgcn_sched_barrier(0);   // no cross-gate scheduling overlap
  if constexpr (Q < NQ - 1) {
    apply_all<D, Q + 1>(s, sst, xch, utab, tid);
  } else if constexpr (D < NDEPTH - 1) {
    apply_all<D + 1, 0>(s, sst, xch, utab, tid);
  }
}

// 8-wave block, LDS 160 KiB -> 1 block/CU -> exactly 2 waves/SIMD.
__global__ __launch_bounds__(NTHR)
__attribute__((amdgpu_waves_per_eu(2, 2)))
void qsim_kernel(const float* __restrict__ x,
                 const float* __restrict__ params,
                 float* __restrict__ out) {
  __shared__ vf2 sst[NLDS * NTHR];             // 124 KB LDS-resident state
  __shared__ vf4 xch[4 * NTHR];                // 32 KB exchange buffer (b128)
  __shared__ vf4 utab[NDEPTH * NQ * 4];        // 4 KB pre-expanded coeffs

  const int tid = threadIdx.x;
  const int b = blockIdx.x;

  // ---- per-block gate table: U = RZ(tz) RY(ty) RX(tx), pre-expanded ----
  if (tid < NDEPTH * NQ) {
    const int d = tid / NQ, q = tid % NQ;
    const float a = tanhf(x[b * NQ + q]);
    const float tx = a + params[(d * NQ + q) * 3 + 0];
    const float ty = a + params[(d * NQ + q) * 3 + 1];
    const float tz = a + params[(d * NQ + q) * 3 + 2];
    const float cx = cosf(0.5f * tx), sx = sinf(0.5f * tx);
    const float cy = cosf(0.5f * ty), sy = sinf(0.5f * ty);
    const float cz = cosf(0.5f * tz), sz = sinf(0.5f * tz);
    // M = RY*RX entries (complex), then U = diag(ez, ezc) * M
    const float m00r = cy * cx,  m00i =  sy * sx;
    const float m01r = -sy * cx, m01i = -cy * sx;
    const float m10r = sy * cx,  m10i = -cy * sx;
    const float m11r = cy * cx,  m11i = -sy * sx;
    // ez = cz - i sz ; ezc = cz + i sz
    const float u00r = cz * m00r + sz * m00i, u00i = cz * m00i - sz * m00r;
    const float u01r = cz * m01r + sz * m01i, u01i = cz * m01i - sz * m01r;
    const float u10r = cz * m10r - sz * m10i, u10i = cz * m10i + sz * m10r;
    const float u11r = cz * m11r - sz * m11i, u11i = cz * m11i + sz * m11r;
    vf4* slot = utab + tid * 4;
    // set_0 (parity 0): A=U00, B=U01 ; set_1 (parity 1): A=U11, B=U10
    slot[0] = (vf4){u00r, u00r, -u00i, u00i};
    slot[1] = (vf4){u01r, u01r, -u01i, u01i};
    slot[2] = (vf4){u11r, u11r, -u11i, u11i};
    slot[3] = (vf4){u10r, u10r, -u10i, u10i};
  }

  // ---- state init: |0..0> (amp x=0 lives at tid 0, r 0) ----
  vf2 s[NREG];
  static_for<NREG>([&](auto rc) { s[decltype(rc)::value] = (vf2){0.f, 0.f}; });
  static_for<NLDS>([&](auto ic) {
    sst[decltype(ic)::value * NTHR + tid] = (vf2){0.f, 0.f};
  });
  if (tid == 0) s[0].x = 1.0f;
  __syncthreads();

  // ---- all 64 rotation gates (CNOTs folded into constexpr masks) ----
  apply_all<0, 0>(s, sst, xch, utab, tid);

  // ---- Z expectations, two passes of 8 to cap register pressure ----
  __syncthreads();                 // xch free for reuse as reduction buffer
  float* red = (float*)xch;
  static_for<2>([&](auto hc) {
    constexpr int H = decltype(hc)::value;
    float z[8];
    static_for<8>([&](auto qc) { z[decltype(qc)::value] = 0.f; });
    static_for<NAMP>([&](auto rc) {
      constexpr int r = decltype(rc)::value;
      const vf2 v = getamp<r>(s, sst, tid);
      const float pr = v.x * v.x + v.y * v.y;
      static_for<8>([&](auto qc) {
        constexpr int qq = decltype(qc)::value;
        constexpr int q = 8 * H + qq;
        constexpr bool neg = cpar(r & MK.meas[q]) != 0;
        z[qq] = neg ? (z[qq] - pr) : (z[qq] + pr);
      });
    });
    static_for<8>([&](auto qc) {
      constexpr int qq = decltype(qc)::value;
      constexpr int q = 8 * H + qq;
      const int ptq = __popc(tid & (MK.meas[q] >> 7)) & 1;
      float v = ptq ? -z[qq] : z[qq];
      static_for<6>([&](auto ic) {
        constexpr int sh = 32 >> decltype(ic)::value;
        v += __shfl_xor(v, sh);
      });
      z[qq] = v;
    });
    if ((tid & 63) == 0) {
      const int w = tid >> 6;      // 8 waves
      static_for<8>([&](auto qc) {
        constexpr int qq = decltype(qc)::value;
        red[w * 8 + qq] = z[qq];
      });
    }
    __syncthreads();
    if (tid < 8) {
      float acc = 0.f;
#pragma unroll
      for (int w = 0; w < 8; ++w) acc += red[w * 8 + tid];
      out[b * NQ + 8 * H + tid] = acc;
    }
    __syncthreads();
  });
}

extern "C" void kernel_launch(void* const* d_in, const int* in_sizes, int n_in,
                              void* d_out, int out_size, void* d_ws, size_t ws_size,
                              hipStream_t stream) {
  const float* x      = (const float*)d_in[0];
  const float* params = (const float*)d_in[1];
  float* out          = (float*)d_out;
  qsim_kernel<<<dim3(NBATCH), dim3(NTHR), 0, stream>>>(x, params, out);
}